// Round 1
// baseline (494.807 us; speedup 1.0000x reference)
//
#include <hip/hip_runtime.h>
#include <math.h>

#define THREADS 256

constexpr int S    = 8;
constexpr int NPT  = 64;   // points per (b,s)
constexpr int SD   = 36;
constexpr float EPS = 1e-5f;

__device__ __forceinline__ float lrelu(float x) { return x > 0.f ? x : 0.01f * x; }

// out[n][d] = bias[d] + sum_c in[n][c] * W[c][d]  for n in [0,64), d in [0,COUT)
// per-thread TN x TD register tile; (64/TN)*(COUT/TD) must equal THREADS.
template<int CIN, int COUT, int TN, int TD>
__device__ __forceinline__ void pn_matmul(const float* __restrict__ in, float* __restrict__ out,
                                          const float* __restrict__ W, const float* __restrict__ bias,
                                          int t) {
  static_assert((NPT / TN) * (COUT / TD) == THREADS, "tile mismatch");
  constexpr int ND = COUT / TD;
  const int n0 = (t / ND) * TN;
  const int d0 = (t % ND) * TD;
  float acc[TN][TD];
#pragma unroll
  for (int i = 0; i < TN; ++i)
#pragma unroll
    for (int j = 0; j < TD; ++j) acc[i][j] = bias[d0 + j];
#pragma unroll 4
  for (int c = 0; c < CIN; ++c) {
    float xv[TN];
#pragma unroll
    for (int i = 0; i < TN; ++i) xv[i] = in[(n0 + i) * CIN + c];
    float wv[TD];
#pragma unroll
    for (int j = 0; j < TD; ++j) wv[j] = W[c * COUT + d0 + j];
#pragma unroll
    for (int i = 0; i < TN; ++i)
#pragma unroll
      for (int j = 0; j < TD; ++j) acc[i][j] = fmaf(xv[i], wv[j], acc[i][j]);
  }
#pragma unroll
  for (int i = 0; i < TN; ++i)
#pragma unroll
    for (int j = 0; j < TD; ++j) out[(n0 + i) * COUT + d0 + j] = acc[i][j];
}

// InstanceNorm over the 64 points per channel (biased var), then leaky-relu, in place.
template<int COUT>
__device__ __forceinline__ void pn_norm(float* __restrict__ x, const float* __restrict__ g,
                                        const float* __restrict__ be, int t) {
  if (t < COUT) {
    float s = 0.f, ss = 0.f;
#pragma unroll 8
    for (int n = 0; n < NPT; ++n) { float v = x[n * COUT + t]; s += v; ss = fmaf(v, v, ss); }
    const float mu  = s * (1.f / NPT);
    const float inv = rsqrtf(ss * (1.f / NPT) - mu * mu + EPS) * g[t];
    const float bb  = be[t];
#pragma unroll 8
    for (int n = 0; n < NPT; ++n)
      x[n * COUT + t] = lrelu((x[n * COUT + t] - mu) * inv + bb);
  }
}

// Conv1D K=2, TF 'same' (pad right only): y[n] = x[n]*W[0] + x[n+1]*W[1], x[8]=0.
// in is [8][CIN] row-major, so [x[n];x[n+1]] is contiguous at in+n*CIN and
// W [2][CIN][COUT] flattens to a [2*CIN][COUT] matmul.
template<int CIN, int COUT, bool ACT>
__device__ __forceinline__ void conv_s8(const float* __restrict__ in, float* __restrict__ out,
                                        const float* __restrict__ W, const float* __restrict__ bias,
                                        int t) {
  constexpr int ND = COUT / 4;
  if (t < S * ND) {
    const int n  = t / ND;
    const int d0 = (t % ND) * 4;
    const float* xr = in + n * CIN;
    float acc[4];
#pragma unroll
    for (int j = 0; j < 4; ++j) acc[j] = bias[d0 + j];
#pragma unroll 4
    for (int c = 0; c < CIN; ++c) {
      const float xv = xr[c];
#pragma unroll
      for (int j = 0; j < 4; ++j) acc[j] = fmaf(xv, W[c * COUT + d0 + j], acc[j]);
    }
    if (n < S - 1) {
#pragma unroll 4
      for (int c = CIN; c < 2 * CIN; ++c) {
        const float xv = xr[c];
#pragma unroll
        for (int j = 0; j < 4; ++j) acc[j] = fmaf(xv, W[c * COUT + d0 + j], acc[j]);
      }
    }
#pragma unroll
    for (int j = 0; j < 4; ++j) out[n * COUT + d0 + j] = ACT ? lrelu(acc[j]) : acc[j];
  }
}

template<int CIN, int COUT, bool ACT>
__device__ __forceinline__ void dense(const float* __restrict__ in, float* __restrict__ out,
                                      const float* __restrict__ W, const float* __restrict__ bias,
                                      int t) {
  if (t < COUT) {
    float acc = bias[t];
#pragma unroll 4
    for (int c = 0; c < CIN; ++c) acc = fmaf(in[c], W[c * COUT + t], acc);
    out[t] = ACT ? lrelu(acc) : acc;
  }
}

__global__ __launch_bounds__(THREADS)
void aggressive_net_kernel(
    const float* __restrict__ fts, const float* __restrict__ state,
    const float* __restrict__ pw1, const float* __restrict__ pb1, const float* __restrict__ pg1, const float* __restrict__ pbe1,
    const float* __restrict__ pw2, const float* __restrict__ pb2, const float* __restrict__ pg2, const float* __restrict__ pbe2,
    const float* __restrict__ pw3, const float* __restrict__ pb3, const float* __restrict__ pg3, const float* __restrict__ pbe3,
    const float* __restrict__ pw4, const float* __restrict__ pb4,
    const float* __restrict__ mw1, const float* __restrict__ mb1,
    const float* __restrict__ mw2, const float* __restrict__ mb2,
    const float* __restrict__ mw3, const float* __restrict__ mb3,
    const float* __restrict__ mw4, const float* __restrict__ mb4,
    const float* __restrict__ mdw, const float* __restrict__ mdb,
    const float* __restrict__ sw1, const float* __restrict__ sb1,
    const float* __restrict__ sw2, const float* __restrict__ sb2,
    const float* __restrict__ sw3, const float* __restrict__ sb3,
    const float* __restrict__ sw4, const float* __restrict__ sb4,
    const float* __restrict__ sdw, const float* __restrict__ sdb,
    const float* __restrict__ cw1, const float* __restrict__ cb1,
    const float* __restrict__ cw2, const float* __restrict__ cb2,
    const float* __restrict__ cw3, const float* __restrict__ cb3,
    const float* __restrict__ cw4, const float* __restrict__ cb4,
    float* __restrict__ out)
{
  const int b = blockIdx.x;
  const int t = threadIdx.x;

  __shared__ float bufA[NPT * 64];    // 16 KB
  __shared__ float bufB[NPT * 128];   // 32 KB
  __shared__ float embAll[S * 128];   //  4 KB

  // ---------------- pointnet, per timestep ----------------
  for (int s = 0; s < S; ++s) {
    const float* src = fts + (size_t)(b * S + s) * (NPT * 5);
    for (int i = t; i < NPT * 5; i += THREADS) bufA[i] = src[i];
    __syncthreads();

    pn_matmul<5, 32, 4, 2>(bufA, bufB, pw1, pb1, t);    // [64,5] -> [64,32]
    __syncthreads();
    pn_norm<32>(bufB, pg1, pbe1, t);
    __syncthreads();

    pn_matmul<32, 64, 4, 4>(bufB, bufA, pw2, pb2, t);   // -> [64,64]
    __syncthreads();
    pn_norm<64>(bufA, pg2, pbe2, t);
    __syncthreads();

    pn_matmul<64, 128, 4, 8>(bufA, bufB, pw3, pb3, t);  // -> [64,128]
    __syncthreads();

    // fused: L3 instance-norm + lrelu + mean over N, result xbar -> bufA[0..127]
    if (t < 128) {
      float s1 = 0.f, ss = 0.f;
#pragma unroll 8
      for (int n = 0; n < NPT; ++n) { float v = bufB[n * 128 + t]; s1 += v; ss = fmaf(v, v, ss); }
      const float mu  = s1 * (1.f / NPT);
      const float inv = rsqrtf(ss * (1.f / NPT) - mu * mu + EPS) * pg3[t];
      const float bb  = pbe3[t];
      float m = 0.f;
#pragma unroll 8
      for (int n = 0; n < NPT; ++n) m += lrelu((bufB[n * 128 + t] - mu) * inv + bb);
      bufA[t] = m * (1.f / NPT);
    }
    __syncthreads();

    // L4 is linear and followed only by mean over N, so mean commutes:
    // emb[s][d] = xbar @ pw4 + pb4   (saves the 64x128x128 matmul)
    if (t < 128) {
      float acc = pb4[t];
#pragma unroll 4
      for (int c = 0; c < 128; ++c) acc = fmaf(bufA[c], pw4[c * 128 + t], acc);
      embAll[s * 128 + t] = acc;
    }
    __syncthreads();
  }

  // ---------------- fts_mergenet ----------------
  conv_s8<128, 128, true>(embAll, bufB, mw1, mb1, t);            // bufB[0..1023]
  __syncthreads();
  conv_s8<128, 64, true>(bufB, bufA, mw2, mb2, t);               // bufA[0..511]
  __syncthreads();
  conv_s8<64, 64, true>(bufA, bufB + 1024, mw3, mb3, t);         // bufB[1024..1535]
  __syncthreads();
  conv_s8<64, 64, true>(bufB + 1024, bufA + 512, mw4, mb4, t);   // bufA[512..1023] = flat[512]
  __syncthreads();
  dense<512, 128, false>(bufA + 512, embAll, mdw, mdb, t);       // fts_emb -> embAll[0..127]
  __syncthreads();

  // ---------------- states branch ----------------
  {
    const float* ssrc = state + (size_t)b * (S * SD);
    for (int i = t; i < S * SD; i += THREADS) bufA[i] = ssrc[i];
  }
  __syncthreads();
  conv_s8<SD, 128, true>(bufA, bufB, sw1, sb1, t);               // bufB[0..1023]
  __syncthreads();
  conv_s8<128, 64, true>(bufB, bufA + 512, sw2, sb2, t);         // bufA[512..1023]
  __syncthreads();
  conv_s8<64, 64, true>(bufA + 512, bufB + 1024, sw3, sb3, t);   // bufB[1024..1535]
  __syncthreads();
  conv_s8<64, 64, false>(bufB + 1024, bufA + 1024, sw4, sb4, t); // no activation
  __syncthreads();
  dense<512, 128, false>(bufA + 1024, embAll + 128, sdw, sdb, t); // st_emb -> embAll[128..255]
  __syncthreads();

  // ---------------- control head ----------------
  dense<256, 128, true>(embAll, bufA, cw1, cb1, t);              // h1 -> bufA[0..127]
  __syncthreads();
  dense<128, 64, true>(bufA, bufA + 128, cw2, cb2, t);           // h2 -> bufA[128..191]
  __syncthreads();
  dense<64, 32, true>(bufA + 128, bufA + 192, cw3, cb3, t);      // h3 -> bufA[192..223]
  __syncthreads();
  if (t < 4) {
    float acc = cb4[t];
#pragma unroll
    for (int c = 0; c < 32; ++c) acc = fmaf(bufA[192 + c], cw4[c * 4 + t], acc);
    float r;
    if (t == 0) r = 21.f / (1.f + expf(-acc));   // sigmoid * 21
    else        r = 6.f * tanhf(acc);            // tanh * 6
    out[(size_t)b * 4 + t] = r;
  }
}

extern "C" void kernel_launch(void* const* d_in, const int* in_sizes, int n_in,
                              void* d_out, int out_size, void* d_ws, size_t ws_size,
                              hipStream_t stream) {
  const float* p[44];
  for (int i = 0; i < 44; ++i) p[i] = (const float*)d_in[i];
  aggressive_net_kernel<<<1024, THREADS, 0, stream>>>(
      p[0], p[1],
      p[2], p[3], p[4], p[5],
      p[6], p[7], p[8], p[9],
      p[10], p[11], p[12], p[13],
      p[14], p[15],
      p[16], p[17], p[18], p[19], p[20], p[21], p[22], p[23], p[24], p[25],
      p[26], p[27], p[28], p[29], p[30], p[31], p[32], p[33], p[34], p[35],
      p[36], p[37], p[38], p[39], p[40], p[41], p[42], p[43],
      (float*)d_out);
}

// Round 2
// 428.685 us; speedup vs baseline: 1.1542x; 1.1542x over previous
//
#include <hip/hip_runtime.h>
#include <math.h>

#define THREADS 256

constexpr int S   = 8;
constexpr int NPT = 64;
constexpr int SD  = 36;
constexpr float EPS = 1e-5f;

__device__ __forceinline__ float lrelu(float x) { return x > 0.f ? x : 0.01f * x; }

// ===================== kernel 1: pointnet, one block per (b,s) =====================
// out[n][d] = bias[d] + sum_c in[n][c]*W[c][d]; padded LDS strides SPI/SPO kill the
// 4-way same-bank conflicts of the unpadded stride-64/128 layout.
template<int CIN, int COUT, int SPI, int SPO, int TN, int TD>
__device__ __forceinline__ void mm_pn(const float* __restrict__ in, float* __restrict__ out,
                                      const float* __restrict__ W, const float* __restrict__ bias, int t) {
  constexpr int ND = COUT / TD;
  static_assert((NPT / TN) * ND == THREADS, "tile mismatch");
  const int n0 = (t / ND) * TN, d0 = (t % ND) * TD;
  float acc[TN][TD];
  float bv[TD];
#pragma unroll
  for (int j = 0; j < TD; ++j) bv[j] = bias[d0 + j];
#pragma unroll
  for (int i = 0; i < TN; ++i)
#pragma unroll
    for (int j = 0; j < TD; ++j) acc[i][j] = bv[j];
#pragma unroll 4
  for (int c = 0; c < CIN; ++c) {
    float xv[TN], wv[TD];
#pragma unroll
    for (int i = 0; i < TN; ++i) xv[i] = in[(n0 + i) * SPI + c];
#pragma unroll
    for (int j = 0; j < TD; ++j) wv[j] = W[c * COUT + d0 + j];
#pragma unroll
    for (int i = 0; i < TN; ++i)
#pragma unroll
      for (int j = 0; j < TD; ++j) acc[i][j] = fmaf(xv[i], wv[j], acc[i][j]);
  }
#pragma unroll
  for (int i = 0; i < TN; ++i)
#pragma unroll
    for (int j = 0; j < TD; ++j) out[(n0 + i) * SPO + d0 + j] = acc[i][j];
}

// InstanceNorm over 64 points per channel + lrelu, in place. All 256 threads do
// stats (G n-groups per channel, LDS combine) and the apply pass.
template<int C, int SP>
__device__ __forceinline__ void inorm_lrelu(float* __restrict__ x, const float* __restrict__ g,
                                            const float* __restrict__ be,
                                            float* __restrict__ ps, float* __restrict__ pss,
                                            float* __restrict__ aA, float* __restrict__ bA, int t) {
  constexpr int G = THREADS / C;
  const int c = t % C, gr = t / C;
  float s = 0.f, ss = 0.f;
#pragma unroll
  for (int k = 0; k < NPT / G; ++k) {
    float v = x[(gr + G * k) * SP + c];
    s += v; ss = fmaf(v, v, ss);
  }
  ps[t] = s; pss[t] = ss;
  __syncthreads();
  if (t < C) {
    float S1 = 0.f, S2 = 0.f;
#pragma unroll
    for (int h = 0; h < G; ++h) { S1 += ps[h * C + t]; S2 += pss[h * C + t]; }
    float mu  = S1 * (1.f / NPT);
    float inv = rsqrtf(S2 * (1.f / NPT) - mu * mu + EPS);
    float a = inv * g[t];
    aA[t] = a; bA[t] = fmaf(-mu, a, be[t]);
  }
  __syncthreads();
  const float a = aA[c], bb = bA[c];
#pragma unroll
  for (int k = 0; k < NPT / G; ++k) {
    int ad = (gr + G * k) * SP + c;
    x[ad] = lrelu(fmaf(x[ad], a, bb));
  }
  __syncthreads();
}

__global__ __launch_bounds__(THREADS)
void pointnet_kernel(const float* __restrict__ fts,
    const float* __restrict__ pw1, const float* __restrict__ pb1, const float* __restrict__ pg1, const float* __restrict__ pbe1,
    const float* __restrict__ pw2, const float* __restrict__ pb2, const float* __restrict__ pg2, const float* __restrict__ pbe2,
    const float* __restrict__ pw3, const float* __restrict__ pb3, const float* __restrict__ pg3, const float* __restrict__ pbe3,
    const float* __restrict__ pw4, const float* __restrict__ pb4,
    float* __restrict__ emb)
{
  const int p = blockIdx.x;   // b*S + s
  const int t = threadIdx.x;

  __shared__ float R1[64 * 65];   // xin [64][5] packed, then x2 [64][65]
  __shared__ float R2[64 * 132];  // x1 [64][33], then x3 [64][132]
  __shared__ float ps[256], pss[256], aA[128], bA[128], xbar[128];

  const float* src = fts + (size_t)p * (NPT * 5);
  for (int i = t; i < NPT * 5; i += THREADS) R1[i] = src[i];
  __syncthreads();

  mm_pn<5, 32, 5, 33, 4, 2>(R1, R2, pw1, pb1, t);      // -> x1 [64][33]
  __syncthreads();
  inorm_lrelu<32, 33>(R2, pg1, pbe1, ps, pss, aA, bA, t);

  mm_pn<32, 64, 33, 65, 4, 4>(R2, R1, pw2, pb2, t);    // -> x2 [64][65]
  __syncthreads();
  inorm_lrelu<64, 65>(R1, pg2, pbe2, ps, pss, aA, bA, t);

  mm_pn<64, 128, 65, 132, 4, 8>(R1, R2, pw3, pb3, t);  // -> x3 [64][132]
  __syncthreads();

  // L3 instance-norm stats (raw x3)
  {
    const int c = t % 128, gr = t / 128;
    float s = 0.f, ss = 0.f;
#pragma unroll
    for (int k = 0; k < 32; ++k) { float v = R2[(gr + 2 * k) * 132 + c]; s += v; ss = fmaf(v, v, ss); }
    ps[t] = s; pss[t] = ss;
  }
  __syncthreads();
  if (t < 128) {
    float S1 = ps[t] + ps[t + 128], S2 = pss[t] + pss[t + 128];
    float mu  = S1 * (1.f / NPT);
    float inv = rsqrtf(S2 * (1.f / NPT) - mu * mu + EPS);
    float a = inv * pg3[t];
    aA[t] = a; bA[t] = fmaf(-mu, a, pbe3[t]);
  }
  __syncthreads();
  // normalized lrelu + mean over n (fused; x3 never rewritten)
  {
    const int c = t % 128, gr = t / 128;
    const float a = aA[c], bb = bA[c];
    float m = 0.f;
#pragma unroll
    for (int k = 0; k < 32; ++k) m += lrelu(fmaf(R2[(gr + 2 * k) * 132 + c], a, bb));
    ps[t] = m;
  }
  __syncthreads();
  if (t < 128) xbar[t] = (ps[t] + ps[t + 128]) * (1.f / NPT);
  __syncthreads();
  // L4 linear commutes with the mean: emb = xbar @ pw4 + pb4, K split in 2
  {
    const int d = t % 128, h = t / 128;
    float acc = 0.f;
#pragma unroll 4
    for (int c = h * 64; c < h * 64 + 64; ++c) acc = fmaf(xbar[c], pw4[c * 128 + d], acc);
    pss[t] = acc;
  }
  __syncthreads();
  if (t < 128) emb[(size_t)p * 128 + t] = pss[t] + pss[t + 128] + pb4[t];
}

// ===================== kernel 2: conv stacks + head, one block per b =====================
// Conv1D K=2, TF 'same' (right pad only): rows contiguous so window is one 2*CIN slice.
template<int CIN, int COUT, int TD, bool ACT>
__device__ __forceinline__ void conv2tap(const float* __restrict__ in, float* __restrict__ out,
                                         const float* __restrict__ W, const float* __restrict__ bias, int t) {
  constexpr int ND = COUT / TD;
  static_assert(S * ND <= THREADS, "conv tile");
  if (t < S * ND) {
    const int n = t / ND, d0 = (t % ND) * TD;
    const float* xr = in + n * CIN;
    float acc[TD];
#pragma unroll
    for (int j = 0; j < TD; ++j) acc[j] = bias[d0 + j];
#pragma unroll 4
    for (int c = 0; c < CIN; ++c) {
      float xv = xr[c];
#pragma unroll
      for (int j = 0; j < TD; ++j) acc[j] = fmaf(xv, W[c * COUT + d0 + j], acc[j]);
    }
    if (n < S - 1) {
#pragma unroll 4
      for (int c = CIN; c < 2 * CIN; ++c) {
        float xv = xr[c];
#pragma unroll
        for (int j = 0; j < TD; ++j) acc[j] = fmaf(xv, W[c * COUT + d0 + j], acc[j]);
      }
    }
#pragma unroll
    for (int j = 0; j < TD; ++j) out[n * COUT + d0 + j] = ACT ? lrelu(acc[j]) : acc[j];
  }
}

// Dense with K split KS ways so COUT*KS threads stay busy; LDS combine.
template<int CIN, int COUT, int KS, bool ACT>
__device__ __forceinline__ void dense_ks(const float* __restrict__ in, float* __restrict__ out,
                                         const float* __restrict__ W, const float* __restrict__ bias,
                                         float* __restrict__ ps, int t) {
  static_assert(COUT * KS <= THREADS, "dense tile");
  constexpr int CH = CIN / KS;
  if (t < COUT * KS) {
    const int d = t % COUT, h = t / COUT;
    float a = 0.f;
#pragma unroll 4
    for (int c = h * CH; c < (h + 1) * CH; ++c) a = fmaf(in[c], W[c * COUT + d], a);
    ps[t] = a;
  }
  __syncthreads();
  if (t < COUT) {
    float a = bias[t];
#pragma unroll
    for (int h = 0; h < KS; ++h) a += ps[h * COUT + t];
    out[t] = ACT ? lrelu(a) : a;
  }
  __syncthreads();
}

__global__ __launch_bounds__(THREADS)
void tail_kernel(const float* __restrict__ emb, const float* __restrict__ state,
    const float* __restrict__ mw1, const float* __restrict__ mb1,
    const float* __restrict__ mw2, const float* __restrict__ mb2,
    const float* __restrict__ mw3, const float* __restrict__ mb3,
    const float* __restrict__ mw4, const float* __restrict__ mb4,
    const float* __restrict__ mdw, const float* __restrict__ mdb,
    const float* __restrict__ sw1, const float* __restrict__ sb1,
    const float* __restrict__ sw2, const float* __restrict__ sb2,
    const float* __restrict__ sw3, const float* __restrict__ sb3,
    const float* __restrict__ sw4, const float* __restrict__ sb4,
    const float* __restrict__ sdw, const float* __restrict__ sdb,
    const float* __restrict__ cw1, const float* __restrict__ cb1,
    const float* __restrict__ cw2, const float* __restrict__ cb2,
    const float* __restrict__ cw3, const float* __restrict__ cb3,
    const float* __restrict__ cw4, const float* __restrict__ cb4,
    float* __restrict__ out)
{
  const int b = blockIdx.x, t = threadIdx.x;
  __shared__ float e[8 * 128], c1[8 * 128], c2[8 * 64], c3[8 * 64], c4[8 * 64];
  __shared__ float sbuf[8 * SD], d1[8 * 128], d2[8 * 64], d3[8 * 64], d4[8 * 64];
  __shared__ float cat[256], h1[128], h2[64], h3[32], ps[256];

  const float* esrc = emb + (size_t)b * (S * 128);
  for (int i = t; i < S * 128; i += THREADS) e[i] = esrc[i];
  const float* ssrc = state + (size_t)b * (S * SD);
  for (int i = t; i < S * SD; i += THREADS) sbuf[i] = ssrc[i];
  __syncthreads();

  // fts_mergenet
  conv2tap<128, 128, 4, true>(e, c1, mw1, mb1, t);  __syncthreads();
  conv2tap<128, 64, 2, true>(c1, c2, mw2, mb2, t);  __syncthreads();
  conv2tap<64, 64, 2, true>(c2, c3, mw3, mb3, t);   __syncthreads();
  conv2tap<64, 64, 2, true>(c3, c4, mw4, mb4, t);   __syncthreads();
  dense_ks<512, 128, 2, false>(c4, cat, mdw, mdb, ps, t);

  // states branch
  conv2tap<SD, 128, 4, true>(sbuf, d1, sw1, sb1, t); __syncthreads();
  conv2tap<128, 64, 2, true>(d1, d2, sw2, sb2, t);   __syncthreads();
  conv2tap<64, 64, 2, true>(d2, d3, sw3, sb3, t);    __syncthreads();
  conv2tap<64, 64, 2, false>(d3, d4, sw4, sb4, t);   __syncthreads();
  dense_ks<512, 128, 2, false>(d4, cat + 128, sdw, sdb, ps, t);

  // control head
  dense_ks<256, 128, 2, true>(cat, h1, cw1, cb1, ps, t);
  dense_ks<128, 64, 4, true>(h1, h2, cw2, cb2, ps, t);
  dense_ks<64, 32, 8, true>(h2, h3, cw3, cb3, ps, t);

  if (t < 4) {
    float acc = cb4[t];
#pragma unroll
    for (int c = 0; c < 32; ++c) acc = fmaf(h3[c], cw4[c * 4 + t], acc);
    out[(size_t)b * 4 + t] = (t == 0) ? 21.f / (1.f + expf(-acc)) : 6.f * tanhf(acc);
  }
}

extern "C" void kernel_launch(void* const* d_in, const int* in_sizes, int n_in,
                              void* d_out, int out_size, void* d_ws, size_t ws_size,
                              hipStream_t stream) {
  const float* p[44];
  for (int i = 0; i < 44; ++i) p[i] = (const float*)d_in[i];
  float* emb = (float*)d_ws;  // 8192 * 128 floats = 4 MB

  pointnet_kernel<<<1024 * S, THREADS, 0, stream>>>(
      p[0],
      p[2], p[3], p[4], p[5],
      p[6], p[7], p[8], p[9],
      p[10], p[11], p[12], p[13],
      p[14], p[15],
      emb);

  tail_kernel<<<1024, THREADS, 0, stream>>>(
      emb, p[1],
      p[16], p[17], p[18], p[19], p[20], p[21], p[22], p[23], p[24], p[25],
      p[26], p[27], p[28], p[29], p[30], p[31], p[32], p[33], p[34], p[35],
      p[36], p[37], p[38], p[39], p[40], p[41], p[42], p[43],
      (float*)d_out);
}

// Round 3
// 340.652 us; speedup vs baseline: 1.4525x; 1.2584x over previous
//
#include <hip/hip_runtime.h>
#include <math.h>

#define THREADS 256

constexpr int S   = 8;
constexpr int NPT = 64;
constexpr int SD  = 36;
constexpr float EPS = 1e-5f;

typedef float v4f __attribute__((ext_vector_type(4)));

__device__ __forceinline__ float lrelu(float x) { return x > 0.f ? x : 0.01f * x; }

// ======================= kernel 1: pointnet, one block per (b,s) =======================
// NOTE: conv biases pb1/pb2/pb3 cancel exactly inside InstanceNorm (per-channel constant
// shift cancels in x - mu), so matmuls before a norm skip the bias.

// scalar matmul (CIN not multiple of 4), acc init 0
template<int CIN, int COUT, int SPI, int SPO, int TN, int TD>
__device__ __forceinline__ void mm_sca(const float* __restrict__ in, float* __restrict__ out,
                                       const float* __restrict__ W, int t) {
  constexpr int ND = COUT / TD;
  static_assert((NPT / TN) * ND == THREADS, "tile");
  const int n0 = (t / ND) * TN, d0 = (t % ND) * TD;
  float acc[TN][TD]{};
#pragma unroll
  for (int c = 0; c < CIN; ++c) {
    float xv[TN], wv[TD];
#pragma unroll
    for (int i = 0; i < TN; ++i) xv[i] = in[(n0 + i) * SPI + c];
#pragma unroll
    for (int j = 0; j < TD; ++j) wv[j] = W[c * COUT + d0 + j];
#pragma unroll
    for (int i = 0; i < TN; ++i)
#pragma unroll
      for (int j = 0; j < TD; ++j) acc[i][j] = fmaf(xv[i], wv[j], acc[i][j]);
  }
#pragma unroll
  for (int i = 0; i < TN; ++i)
#pragma unroll
    for (int j = 0; j < TD; ++j) out[(n0 + i) * SPO + d0 + j] = acc[i][j];
}

// vectorized matmul: float4 LDS reads over c, float4 weight reads, float4 stores
template<int CIN, int COUT, int SPI, int SPO, int TN, int TD>
__device__ __forceinline__ void mm_vec(const float* __restrict__ in, float* __restrict__ out,
                                       const float* __restrict__ W, int t) {
  constexpr int ND = COUT / TD;
  static_assert((NPT / TN) * ND == THREADS, "tile");
  static_assert(CIN % 4 == 0 && TD % 4 == 0 && SPI % 4 == 0 && SPO % 4 == 0, "vec");
  const int n0 = (t / ND) * TN, d0 = (t % ND) * TD;
  float acc[TN][TD]{};
#pragma unroll 4
  for (int c4 = 0; c4 < CIN / 4; ++c4) {
    v4f xv[TN];
#pragma unroll
    for (int i = 0; i < TN; ++i) xv[i] = *(const v4f*)(in + (n0 + i) * SPI + 4 * c4);
#pragma unroll
    for (int j = 0; j < 4; ++j) {
      v4f wv[TD / 4];
#pragma unroll
      for (int q = 0; q < TD / 4; ++q) wv[q] = *(const v4f*)(W + (4 * c4 + j) * COUT + d0 + 4 * q);
#pragma unroll
      for (int i = 0; i < TN; ++i) {
        const float xs = xv[i][j];
#pragma unroll
        for (int k = 0; k < TD; ++k) acc[i][k] = fmaf(xs, wv[k >> 2][k & 3], acc[i][k]);
      }
    }
  }
#pragma unroll
  for (int i = 0; i < TN; ++i)
#pragma unroll
    for (int q = 0; q < TD / 4; ++q) {
      v4f o;
#pragma unroll
      for (int r = 0; r < 4; ++r) o[r] = acc[i][4 * q + r];
      *(v4f*)(out + (n0 + i) * SPO + d0 + 4 * q) = o;
    }
}

// InstanceNorm over 64 points per channel + lrelu, in place (all 256 threads active)
template<int C, int SP>
__device__ __forceinline__ void inorm_lrelu(float* __restrict__ x, const float* __restrict__ g,
                                            const float* __restrict__ be,
                                            float* __restrict__ ps, float* __restrict__ pss,
                                            float* __restrict__ aA, float* __restrict__ bA, int t) {
  constexpr int G = THREADS / C;
  const int c = t % C, gr = t / C;
  float s = 0.f, ss = 0.f;
#pragma unroll
  for (int k = 0; k < NPT / G; ++k) {
    float v = x[(gr + G * k) * SP + c];
    s += v; ss = fmaf(v, v, ss);
  }
  ps[t] = s; pss[t] = ss;
  __syncthreads();
  if (t < C) {
    float S1 = 0.f, S2 = 0.f;
#pragma unroll
    for (int h = 0; h < G; ++h) { S1 += ps[h * C + t]; S2 += pss[h * C + t]; }
    float mu  = S1 * (1.f / NPT);
    float inv = rsqrtf(S2 * (1.f / NPT) - mu * mu + EPS);
    float a = inv * g[t];
    aA[t] = a; bA[t] = fmaf(-mu, a, be[t]);
  }
  __syncthreads();
  const float a = aA[c], bb = bA[c];
#pragma unroll
  for (int k = 0; k < NPT / G; ++k) {
    int ad = (gr + G * k) * SP + c;
    x[ad] = lrelu(fmaf(x[ad], a, bb));
  }
  __syncthreads();
}

__global__ __launch_bounds__(THREADS)
void pointnet_kernel(const float* __restrict__ fts,
    const float* __restrict__ pw1, const float* __restrict__ pg1, const float* __restrict__ pbe1,
    const float* __restrict__ pw2, const float* __restrict__ pg2, const float* __restrict__ pbe2,
    const float* __restrict__ pw3, const float* __restrict__ pg3, const float* __restrict__ pbe3,
    const float* __restrict__ pw4, const float* __restrict__ pb4,
    float* __restrict__ emb)
{
  const int p = blockIdx.x;   // b*S + s
  const int t = threadIdx.x;

  __shared__ float xin[64 * 5];    //  1.25 KB
  __shared__ float x1[64 * 36];    //  9.0 KB (32 cols + pad4)
  __shared__ float x2[64 * 68];    // 17.0 KB (64 cols + pad4)
  __shared__ float ps[4 * 128], pss[4 * 128];
  __shared__ float aA[128], bA[128], xbar[128];

  { const float* src = fts + (size_t)p * 320;
    for (int i = t; i < 320; i += THREADS) xin[i] = src[i]; }
  __syncthreads();

  mm_sca<5, 32, 5, 36, 4, 2>(xin, x1, pw1, t);          // L1 -> x1 [64][36]
  __syncthreads();
  inorm_lrelu<32, 36>(x1, pg1, pbe1, ps, pss, aA, bA, t);

  mm_vec<32, 64, 36, 68, 4, 4>(x1, x2, pw2, t);         // L2 -> x2 [64][68]
  __syncthreads();
  inorm_lrelu<64, 68>(x2, pg2, pbe2, ps, pss, aA, bA, t);

  // ---- L3 [64,64]x[64,128] kept in registers: acc[4 rows][8 cols] ----
  const int d0 = (t & 15) * 8;
  const int n0 = (t >> 4) * 4;
  const int l  = t & 63, w = t >> 6;
  float acc[4][8]{};
#pragma unroll 4
  for (int c4 = 0; c4 < 16; ++c4) {
    v4f xv[4];
#pragma unroll
    for (int i = 0; i < 4; ++i) xv[i] = *(const v4f*)(x2 + (n0 + i) * 68 + 4 * c4);
#pragma unroll
    for (int j = 0; j < 4; ++j) {
      v4f w0 = *(const v4f*)(pw3 + (4 * c4 + j) * 128 + d0);
      v4f w1 = *(const v4f*)(pw3 + (4 * c4 + j) * 128 + d0 + 4);
#pragma unroll
      for (int i = 0; i < 4; ++i) {
        const float xs = xv[i][j];
#pragma unroll
        for (int k = 0; k < 4; ++k) acc[i][k]     = fmaf(xs, w0[k], acc[i][k]);
#pragma unroll
        for (int k = 0; k < 4; ++k) acc[i][4 + k] = fmaf(xs, w1[k], acc[i][4 + k]);
      }
    }
  }
  // stats: per-thread over 4 rows, then xor-shuffle over the 4 n-groups in the wave
  float sv[8], sq[8];
#pragma unroll
  for (int k = 0; k < 8; ++k) {
    float s = 0.f, q = 0.f;
#pragma unroll
    for (int i = 0; i < 4; ++i) { float v = acc[i][k]; s += v; q = fmaf(v, v, q); }
    sv[k] = s; sq[k] = q;
  }
#pragma unroll
  for (int m = 16; m <= 32; m <<= 1)
#pragma unroll
    for (int k = 0; k < 8; ++k) { sv[k] += __shfl_xor(sv[k], m, 64); sq[k] += __shfl_xor(sq[k], m, 64); }
  if (l < 16) {
#pragma unroll
    for (int k = 0; k < 8; ++k) { ps[w * 128 + d0 + k] = sv[k]; pss[w * 128 + d0 + k] = sq[k]; }
  }
  __syncthreads();
  if (t < 128) {
    float S1 = ps[t] + ps[128 + t] + ps[256 + t] + ps[384 + t];
    float S2 = pss[t] + pss[128 + t] + pss[256 + t] + pss[384 + t];
    float mu  = S1 * (1.f / NPT);
    float inv = rsqrtf(S2 * (1.f / NPT) - mu * mu + EPS);
    float a = inv * pg3[t];
    aA[t] = a; bA[t] = fmaf(-mu, a, pbe3[t]);
  }
  __syncthreads();
  // normalize + lrelu + mean over n, all in registers
  float mv[8];
  {
    float av[8], bv[8];
#pragma unroll
    for (int k = 0; k < 8; ++k) { av[k] = aA[d0 + k]; bv[k] = bA[d0 + k]; }
#pragma unroll
    for (int k = 0; k < 8; ++k) {
      float m_ = 0.f;
#pragma unroll
      for (int i = 0; i < 4; ++i) m_ += lrelu(fmaf(acc[i][k], av[k], bv[k]));
      mv[k] = m_;
    }
  }
#pragma unroll
  for (int m = 16; m <= 32; m <<= 1)
#pragma unroll
    for (int k = 0; k < 8; ++k) mv[k] += __shfl_xor(mv[k], m, 64);
  if (l < 16) {
#pragma unroll
    for (int k = 0; k < 8; ++k) ps[w * 128 + d0 + k] = mv[k];
  }
  __syncthreads();
  if (t < 128) xbar[t] = (ps[t] + ps[128 + t] + ps[256 + t] + ps[384 + t]) * (1.f / NPT);
  __syncthreads();
  // L4 commutes with the mean: emb = xbar @ pw4 + pb4 (K split 2)
  {
    const int d = t & 127, h = t >> 7;
    float a = 0.f;
#pragma unroll 8
    for (int c = h * 64; c < h * 64 + 64; ++c) a = fmaf(xbar[c], pw4[c * 128 + d], a);
    pss[t] = a;
  }
  __syncthreads();
  if (t < 128) emb[(size_t)p * 128 + t] = pss[t] + pss[128 + t] + pb4[t];
}

// ======================= kernel 2: tail, one WAVE per (b, branch) =======================
// block = 256 threads = 4 waves; waves (0,1) -> b0 (merge, states), (2,3) -> b1.
// Conv1D K=2 'same' (right-pad): out row n = x[n]*W[0:CIN] + x[n+1]*W[CIN:2CIN].
template<int CIN, int COUT, int SPI, int SPO, bool ACT>
__device__ __forceinline__ void wave_conv(const float* __restrict__ in, float* __restrict__ out,
                                          const float* __restrict__ W, const float* __restrict__ bias, int l) {
  constexpr int NC = COUT / 8;           // cols per lane
  static_assert(CIN % 4 == 0 && NC % 4 == 0 || NC == 4, "vec");
  const int n = l & 7, d0 = (l >> 3) * NC;
  float acc[NC];
#pragma unroll
  for (int k = 0; k < NC; ++k) acc[k] = bias[d0 + k];
  const float* xr = in + n * SPI;
#pragma unroll 2
  for (int c4 = 0; c4 < CIN / 4; ++c4) {
    v4f x4 = *(const v4f*)(xr + 4 * c4);
#pragma unroll
    for (int j = 0; j < 4; ++j) {
      const float* wr = W + (4 * c4 + j) * COUT + d0;
#pragma unroll
      for (int q = 0; q < NC / 4; ++q) {
        v4f wq = *(const v4f*)(wr + 4 * q);
#pragma unroll
        for (int r = 0; r < 4; ++r) acc[4 * q + r] = fmaf(x4[j], wq[r], acc[4 * q + r]);
      }
    }
  }
  if (n < 7) {
    const float* xr2 = in + (n + 1) * SPI;
    const float* W2  = W + CIN * COUT;
#pragma unroll 2
    for (int c4 = 0; c4 < CIN / 4; ++c4) {
      v4f x4 = *(const v4f*)(xr2 + 4 * c4);
#pragma unroll
      for (int j = 0; j < 4; ++j) {
        const float* wr = W2 + (4 * c4 + j) * COUT + d0;
#pragma unroll
        for (int q = 0; q < NC / 4; ++q) {
          v4f wq = *(const v4f*)(wr + 4 * q);
#pragma unroll
          for (int r = 0; r < 4; ++r) acc[4 * q + r] = fmaf(x4[j], wq[r], acc[4 * q + r]);
        }
      }
    }
  }
#pragma unroll
  for (int q = 0; q < NC / 4; ++q) {
    v4f o;
#pragma unroll
    for (int r = 0; r < 4; ++r) o[r] = ACT ? lrelu(acc[4 * q + r]) : acc[4 * q + r];
    *(v4f*)(out + n * SPO + d0 + 4 * q) = o;
  }
}

// dense over flattened conv output [8][64] stored with row stride 68
template<int COUT, bool ACT>
__device__ __forceinline__ void wave_dense512(const float* __restrict__ in, float* __restrict__ out,
                                              const float* __restrict__ W, const float* __restrict__ bias, int l) {
  constexpr int NC = COUT / 64;
  const int d0 = l * NC;
  float acc[NC];
#pragma unroll
  for (int k = 0; k < NC; ++k) acc[k] = bias[d0 + k];
#pragma unroll
  for (int n = 0; n < 8; ++n) {
    const float* xr = in + n * 68;
#pragma unroll 4
    for (int c4 = 0; c4 < 16; ++c4) {
      v4f x4 = *(const v4f*)(xr + 4 * c4);
#pragma unroll
      for (int j = 0; j < 4; ++j) {
        const float* wr = W + ((n * 64) + 4 * c4 + j) * COUT + d0;
#pragma unroll
        for (int k = 0; k < NC; ++k) acc[k] = fmaf(x4[j], wr[k], acc[k]);
      }
    }
  }
#pragma unroll
  for (int k = 0; k < NC; ++k) out[d0 + k] = ACT ? lrelu(acc[k]) : acc[k];
}

// small dense: contiguous input of CIN floats
template<int CIN, int COUT, bool ACT>
__device__ __forceinline__ void wave_dense(const float* __restrict__ in, float* __restrict__ out,
                                           const float* __restrict__ W, const float* __restrict__ bias, int l) {
  if constexpr (COUT >= 64) {
    constexpr int NC = COUT / 64;
    const int d0 = l * NC;
    float acc[NC];
#pragma unroll
    for (int k = 0; k < NC; ++k) acc[k] = bias[d0 + k];
#pragma unroll 4
    for (int c4 = 0; c4 < CIN / 4; ++c4) {
      v4f x4 = *(const v4f*)(in + 4 * c4);
#pragma unroll
      for (int j = 0; j < 4; ++j) {
        const float* wr = W + (4 * c4 + j) * COUT + d0;
#pragma unroll
        for (int k = 0; k < NC; ++k) acc[k] = fmaf(x4[j], wr[k], acc[k]);
      }
    }
#pragma unroll
    for (int k = 0; k < NC; ++k) out[d0 + k] = ACT ? lrelu(acc[k]) : acc[k];
  } else {
    if (l < COUT) {
      float acc = bias[l];
#pragma unroll 4
      for (int c4 = 0; c4 < CIN / 4; ++c4) {
        v4f x4 = *(const v4f*)(in + 4 * c4);
#pragma unroll
        for (int j = 0; j < 4; ++j) acc = fmaf(x4[j], W[(4 * c4 + j) * COUT + l], acc);
      }
      out[l] = ACT ? lrelu(acc) : acc;
    }
  }
}

__global__ __launch_bounds__(THREADS)
void tail_kernel(const float* __restrict__ emb, const float* __restrict__ state,
    const float* __restrict__ mw1, const float* __restrict__ mb1,
    const float* __restrict__ mw2, const float* __restrict__ mb2,
    const float* __restrict__ mw3, const float* __restrict__ mb3,
    const float* __restrict__ mw4, const float* __restrict__ mb4,
    const float* __restrict__ mdw, const float* __restrict__ mdb,
    const float* __restrict__ sw1, const float* __restrict__ sb1,
    const float* __restrict__ sw2, const float* __restrict__ sb2,
    const float* __restrict__ sw3, const float* __restrict__ sb3,
    const float* __restrict__ sw4, const float* __restrict__ sb4,
    const float* __restrict__ sdw, const float* __restrict__ sdb,
    const float* __restrict__ cw1, const float* __restrict__ cb1,
    const float* __restrict__ cw2, const float* __restrict__ cb2,
    const float* __restrict__ cw3, const float* __restrict__ cb3,
    const float* __restrict__ cw4, const float* __restrict__ cb4,
    float* __restrict__ out)
{
  const int t = threadIdx.x, l = t & 63, w = t >> 6;
  const int sub = w >> 1;              // which b within the block
  const int br  = w & 1;               // 0 = merge branch, 1 = states branch
  const int b   = blockIdx.x * 2 + sub;

  __shared__ float M0[2][8 * 132], M1[2][8 * 132];
  __shared__ float S0[2][8 * 132], S1[2][8 * 132];
  __shared__ float sin_[2][8 * 40];
  __shared__ float cat[2][256];

  float* m0 = M0[sub]; float* m1 = M1[sub];
  float* s0 = S0[sub]; float* s1 = S1[sub];

  // stage 0: load inputs
  if (br == 0) {
    const float* esrc = emb + (size_t)b * 1024;
    for (int i = l; i < 256; i += 64) {
      v4f v = *(const v4f*)(esrc + 4 * i);
      int n = (4 * i) >> 7, c = (4 * i) & 127;
      *(v4f*)(m0 + n * 132 + c) = v;
    }
  } else {
    const float* ssrc = state + (size_t)b * (S * SD);
    for (int i = l; i < S * SD; i += 64) sin_[sub][(i / SD) * 40 + (i % SD)] = ssrc[i];
  }
  __syncthreads();

  if (br == 0) wave_conv<128, 128, 132, 132, true>(m0, m1, mw1, mb1, l);
  else         wave_conv<SD,  128,  40, 132, true>(sin_[sub], s0, sw1, sb1, l);
  __syncthreads();
  if (br == 0) wave_conv<128, 64, 132, 68, true>(m1, m0, mw2, mb2, l);
  else         wave_conv<128, 64, 132, 68, true>(s0, s1, sw2, sb2, l);
  __syncthreads();
  if (br == 0) wave_conv<64, 64, 68, 68, true>(m0, m1, mw3, mb3, l);
  else         wave_conv<64, 64, 68, 68, true>(s1, s0, sw3, sb3, l);
  __syncthreads();
  if (br == 0) wave_conv<64, 64, 68, 68, true>(m1, m0, mw4, mb4, l);
  else         wave_conv<64, 64, 68, 68, false>(s0, s1, sw4, sb4, l);
  __syncthreads();
  if (br == 0) wave_dense512<128, false>(m0, cat[sub],       mdw, mdb, l);
  else         wave_dense512<128, false>(s1, cat[sub] + 128, sdw, sdb, l);
  __syncthreads();

  // control head on the merge wave of each b (h1/h2/h3 reuse m1)
  float* h1 = m1; float* h2 = m1 + 128; float* h3 = m1 + 192;
  if (br == 0) wave_dense<256, 128, true>(cat[sub], h1, cw1, cb1, l);
  __syncthreads();
  if (br == 0) wave_dense<128, 64, true>(h1, h2, cw2, cb2, l);
  __syncthreads();
  if (br == 0) wave_dense<64, 32, true>(h2, h3, cw3, cb3, l);
  __syncthreads();
  if (br == 0 && l < 4) {
    float acc = cb4[l];
#pragma unroll
    for (int c = 0; c < 32; ++c) acc = fmaf(h3[c], cw4[c * 4 + l], acc);
    out[(size_t)b * 4 + l] = (l == 0) ? 21.f / (1.f + expf(-acc)) : 6.f * tanhf(acc);
  }
}

extern "C" void kernel_launch(void* const* d_in, const int* in_sizes, int n_in,
                              void* d_out, int out_size, void* d_ws, size_t ws_size,
                              hipStream_t stream) {
  const float* p[44];
  for (int i = 0; i < 44; ++i) p[i] = (const float*)d_in[i];
  float* emb = (float*)d_ws;  // 8192 * 128 floats = 4 MB

  pointnet_kernel<<<1024 * S, THREADS, 0, stream>>>(
      p[0],
      p[2], p[4], p[5],
      p[6], p[8], p[9],
      p[10], p[12], p[13],
      p[14], p[15],
      emb);

  tail_kernel<<<512, THREADS, 0, stream>>>(
      emb, p[1],
      p[16], p[17], p[18], p[19], p[20], p[21], p[22], p[23], p[24], p[25],
      p[26], p[27], p[28], p[29], p[30], p[31], p[32], p[33], p[34], p[35],
      p[36], p[37], p[38], p[39], p[40], p[41], p[42], p[43],
      (float*)d_out);
}

// Round 4
// 196.129 us; speedup vs baseline: 2.5229x; 1.7369x over previous
//
#include <hip/hip_runtime.h>
#include <math.h>

#define THREADS 256

constexpr int S   = 8;
constexpr int NPT = 64;
constexpr int SD  = 36;
constexpr float EPS = 1e-5f;

typedef float v4f __attribute__((ext_vector_type(4)));
typedef __attribute__((ext_vector_type(8))) short bf8;   // 8 bf16 (4 VGPR)
typedef __attribute__((ext_vector_type(4))) float f4;    // MFMA accumulator

__device__ __forceinline__ float lrelu(float x) { return x > 0.f ? x : 0.01f * x; }

// float -> bf16 round-to-nearest-even
__device__ __forceinline__ unsigned short f2bf(float x) {
  union { float f; unsigned u; } v; v.f = x;
  unsigned r = v.u + 0x7FFFu + ((v.u >> 16) & 1u);
  return (unsigned short)(r >> 16);
}

// ============ weight prep: pw2/pw3 -> bf16 MFMA B-fragments in d_ws ============
// Fragment order: lane l holds n = nt*16 + (l&15), k = kt*32 + (l>>4)*8 + j.
// Same (g,j)->k mapping used for A fragments, so any HW k-permutation cancels.
__global__ void prep_weights(const float* __restrict__ pw2, const float* __restrict__ pw3,
                             unsigned short* __restrict__ w2f, unsigned short* __restrict__ w3f) {
  int t = blockIdx.x * blockDim.x + threadIdx.x;
  if (t < 4 * 64) {            // pw2 [32][64]: kt=0, nt=0..3
    int nt = t >> 6, lane = t & 63;
    int n = nt * 16 + (lane & 15), g = lane >> 4;
    unsigned short* dst = w2f + (size_t)t * 8;
#pragma unroll
    for (int j = 0; j < 8; ++j) dst[j] = f2bf(pw2[(g * 8 + j) * 64 + n]);
  }
  if (t < 16 * 64) {           // pw3 [64][128]: frag f = kt*8 + nt
    int f = t >> 6, lane = t & 63;
    int kt = f >> 3, nt = f & 7;
    int n = nt * 16 + (lane & 15), g = lane >> 4;
    unsigned short* dst = w3f + (size_t)t * 8;
#pragma unroll
    for (int j = 0; j < 8; ++j) dst[j] = f2bf(pw3[(kt * 32 + g * 8 + j) * 128 + n]);
  }
}

// ============ pointnet helpers ============
// scalar matmul (CIN=5), bias-free (bias cancels in the following instance norm)
template<int CIN, int COUT, int SPI, int SPO, int TN, int TD>
__device__ __forceinline__ void mm_sca(const float* __restrict__ in, float* __restrict__ out,
                                       const float* __restrict__ W, int t) {
  constexpr int ND = COUT / TD;
  static_assert((NPT / TN) * ND == THREADS, "tile");
  const int n0 = (t / ND) * TN, d0 = (t % ND) * TD;
  float acc[TN][TD]{};
#pragma unroll
  for (int c = 0; c < CIN; ++c) {
    float xv[TN], wv[TD];
#pragma unroll
    for (int i = 0; i < TN; ++i) xv[i] = in[(n0 + i) * SPI + c];
#pragma unroll
    for (int j = 0; j < TD; ++j) wv[j] = W[c * COUT + d0 + j];
#pragma unroll
    for (int i = 0; i < TN; ++i)
#pragma unroll
      for (int j = 0; j < TD; ++j) acc[i][j] = fmaf(xv[i], wv[j], acc[i][j]);
  }
#pragma unroll
  for (int i = 0; i < TN; ++i)
#pragma unroll
    for (int j = 0; j < TD; ++j) out[(n0 + i) * SPO + d0 + j] = acc[i][j];
}

// ============ kernel 1: pointnet, one block per (b,s), MFMA for L2/L3 ============
__global__ __launch_bounds__(THREADS)
void pointnet_kernel(const float* __restrict__ fts,
    const float* __restrict__ pw1, const float* __restrict__ pg1, const float* __restrict__ pbe1,
    const unsigned short* __restrict__ w2f, const float* __restrict__ pg2, const float* __restrict__ pbe2,
    const unsigned short* __restrict__ w3f, const float* __restrict__ pg3, const float* __restrict__ pbe3,
    const float* __restrict__ pw4, const float* __restrict__ pb4,
    float* __restrict__ emb)
{
  const int p = blockIdx.x;            // b*S + s
  const int t = threadIdx.x;
  const int l = t & 63, w = t >> 6;    // lane, wave
  const int g = l >> 4, lc = l & 15;   // lane group (k-slice / row group), lane col

  __shared__ float xin[320];                 // raw input [64][5]
  __shared__ float x1[64 * 36];              // L1 out fp32
  __shared__ unsigned short x1b[64 * 40];    // L1 normed, bf16 (A for L2)
  __shared__ unsigned short x2b[64 * 72];    // L2 normed, bf16 (A for L3)
  __shared__ float ps[256], pss[256];
  __shared__ float aA[32], bA[32];
  __shared__ float xbar[128];

  { const float* src = fts + (size_t)p * 320;
    for (int i = t; i < 320; i += THREADS) xin[i] = src[i]; }
  __syncthreads();

  // ---- L1: [64x5]@[5x32] fp32 VALU ----
  mm_sca<5, 32, 5, 36, 4, 2>(xin, x1, pw1, t);
  __syncthreads();

  // ---- inorm1 + lrelu -> bf16 x1b ----
  {
    const int c = t & 31, gr = t >> 5;   // 8 row-groups
    float s = 0.f, ss = 0.f;
#pragma unroll
    for (int k = 0; k < 8; ++k) { float v = x1[(gr + 8 * k) * 36 + c]; s += v; ss = fmaf(v, v, ss); }
    ps[t] = s; pss[t] = ss;
    __syncthreads();
    if (t < 32) {
      float S1 = 0.f, S2 = 0.f;
#pragma unroll
      for (int h = 0; h < 8; ++h) { S1 += ps[h * 32 + t]; S2 += pss[h * 32 + t]; }
      float mu  = S1 * (1.f / NPT);
      float inv = rsqrtf(S2 * (1.f / NPT) - mu * mu + EPS);
      float a = inv * pg1[t];
      aA[t] = a; bA[t] = fmaf(-mu, a, pbe1[t]);
    }
    __syncthreads();
    const float a = aA[c], bb = bA[c];
#pragma unroll
    for (int k = 0; k < 8; ++k) {
      int r = gr + 8 * k;
      x1b[r * 40 + c] = f2bf(lrelu(fmaf(x1[r * 36 + c], a, bb)));
    }
  }
  __syncthreads();

  // ---- L2 MFMA: [64x32]@[32x64]; wave w owns channels 16w..16w+15 ----
  f4 c2[4];
#pragma unroll
  for (int mt = 0; mt < 4; ++mt) c2[mt] = f4{0.f, 0.f, 0.f, 0.f};
  {
    bf8 bfrag = *(const bf8*)(w2f + ((size_t)w * 64 + l) * 8);
#pragma unroll
    for (int mt = 0; mt < 4; ++mt) {
      bf8 afrag = *(const bf8*)(x1b + (mt * 16 + lc) * 40 + g * 8);
      c2[mt] = __builtin_amdgcn_mfma_f32_16x16x32_bf16(afrag, bfrag, c2[mt], 0, 0, 0);
    }
  }
  // inorm2 in-register (channel = 16w + lc; rows spread over g and reg)
  {
    float s = 0.f, q = 0.f;
#pragma unroll
    for (int mt = 0; mt < 4; ++mt)
#pragma unroll
      for (int r = 0; r < 4; ++r) { float v = c2[mt][r]; s += v; q = fmaf(v, v, q); }
    s += __shfl_xor(s, 16, 64); s += __shfl_xor(s, 32, 64);
    q += __shfl_xor(q, 16, 64); q += __shfl_xor(q, 32, 64);
    const int ch = w * 16 + lc;
    float mu  = s * (1.f / NPT);
    float inv = rsqrtf(q * (1.f / NPT) - mu * mu + EPS);
    float a = inv * pg2[ch];
    float bb = fmaf(-mu, a, pbe2[ch]);
#pragma unroll
    for (int mt = 0; mt < 4; ++mt)
#pragma unroll
      for (int r = 0; r < 4; ++r) {
        int row = mt * 16 + g * 4 + r;
        x2b[row * 72 + ch] = f2bf(lrelu(fmaf(c2[mt][r], a, bb)));
      }
  }
  __syncthreads();

  // ---- L3 MFMA: [64x64]@[64x128]; wave w owns channels 32w..32w+31 ----
  f4 c3[4][2];
#pragma unroll
  for (int mt = 0; mt < 4; ++mt)
#pragma unroll
    for (int n = 0; n < 2; ++n) c3[mt][n] = f4{0.f, 0.f, 0.f, 0.f};
  bf8 bf3[2][2];
#pragma unroll
  for (int ntl = 0; ntl < 2; ++ntl)
#pragma unroll
    for (int kt = 0; kt < 2; ++kt)
      bf3[ntl][kt] = *(const bf8*)(w3f + ((size_t)(kt * 8 + (2 * w + ntl)) * 64 + l) * 8);
#pragma unroll
  for (int mt = 0; mt < 4; ++mt)
#pragma unroll
    for (int kt = 0; kt < 2; ++kt) {
      bf8 afrag = *(const bf8*)(x2b + (mt * 16 + lc) * 72 + kt * 32 + g * 8);
#pragma unroll
      for (int ntl = 0; ntl < 2; ++ntl)
        c3[mt][ntl] = __builtin_amdgcn_mfma_f32_16x16x32_bf16(afrag, bf3[ntl][kt], c3[mt][ntl], 0, 0, 0);
    }

  // ---- inorm3 + lrelu + mean over n, in-register; xbar[128] ----
#pragma unroll
  for (int ntl = 0; ntl < 2; ++ntl) {
    float s = 0.f, q = 0.f;
#pragma unroll
    for (int mt = 0; mt < 4; ++mt)
#pragma unroll
      for (int r = 0; r < 4; ++r) { float v = c3[mt][ntl][r]; s += v; q = fmaf(v, v, q); }
    s += __shfl_xor(s, 16, 64); s += __shfl_xor(s, 32, 64);
    q += __shfl_xor(q, 16, 64); q += __shfl_xor(q, 32, 64);
    const int ch = w * 32 + ntl * 16 + lc;
    float mu  = s * (1.f / NPT);
    float inv = rsqrtf(q * (1.f / NPT) - mu * mu + EPS);
    float a = inv * pg3[ch];
    float bb = fmaf(-mu, a, pbe3[ch]);
    float m = 0.f;
#pragma unroll
    for (int mt = 0; mt < 4; ++mt)
#pragma unroll
      for (int r = 0; r < 4; ++r) m += lrelu(fmaf(c3[mt][ntl][r], a, bb));
    m += __shfl_xor(m, 16, 64); m += __shfl_xor(m, 32, 64);
    if (g == 0) xbar[ch] = m * (1.f / NPT);
  }
  __syncthreads();

  // ---- L4 commutes with mean: emb = xbar @ pw4 + pb4 (fp32, K split 2) ----
  {
    const int d = t & 127, h = t >> 7;
    float a = 0.f;
#pragma unroll 8
    for (int c = h * 64; c < h * 64 + 64; ++c) a = fmaf(xbar[c], pw4[c * 128 + d], a);
    ps[t] = a;
  }
  __syncthreads();
  if (t < 128) emb[(size_t)p * 128 + t] = ps[t] + ps[t + 128] + pb4[t];
}

// ======================= kernel 2: tail, one WAVE per (b, branch) =======================
template<int CIN, int COUT, int SPI, int SPO, bool ACT>
__device__ __forceinline__ void wave_conv(const float* __restrict__ in, float* __restrict__ out,
                                          const float* __restrict__ W, const float* __restrict__ bias, int l) {
  constexpr int NC = COUT / 8;
  static_assert(CIN % 4 == 0 && NC % 4 == 0 || NC == 4, "vec");
  const int n = l & 7, d0 = (l >> 3) * NC;
  float acc[NC];
#pragma unroll
  for (int k = 0; k < NC; ++k) acc[k] = bias[d0 + k];
  const float* xr = in + n * SPI;
#pragma unroll 2
  for (int c4 = 0; c4 < CIN / 4; ++c4) {
    v4f x4 = *(const v4f*)(xr + 4 * c4);
#pragma unroll
    for (int j = 0; j < 4; ++j) {
      const float* wr = W + (4 * c4 + j) * COUT + d0;
#pragma unroll
      for (int q = 0; q < NC / 4; ++q) {
        v4f wq = *(const v4f*)(wr + 4 * q);
#pragma unroll
        for (int r = 0; r < 4; ++r) acc[4 * q + r] = fmaf(x4[j], wq[r], acc[4 * q + r]);
      }
    }
  }
  if (n < 7) {
    const float* xr2 = in + (n + 1) * SPI;
    const float* W2  = W + CIN * COUT;
#pragma unroll 2
    for (int c4 = 0; c4 < CIN / 4; ++c4) {
      v4f x4 = *(const v4f*)(xr2 + 4 * c4);
#pragma unroll
      for (int j = 0; j < 4; ++j) {
        const float* wr = W2 + (4 * c4 + j) * COUT + d0;
#pragma unroll
        for (int q = 0; q < NC / 4; ++q) {
          v4f wq = *(const v4f*)(wr + 4 * q);
#pragma unroll
          for (int r = 0; r < 4; ++r) acc[4 * q + r] = fmaf(x4[j], wq[r], acc[4 * q + r]);
        }
      }
    }
  }
#pragma unroll
  for (int q = 0; q < NC / 4; ++q) {
    v4f o;
#pragma unroll
    for (int r = 0; r < 4; ++r) o[r] = ACT ? lrelu(acc[4 * q + r]) : acc[4 * q + r];
    *(v4f*)(out + n * SPO + d0 + 4 * q) = o;
  }
}

template<int COUT, bool ACT>
__device__ __forceinline__ void wave_dense512(const float* __restrict__ in, float* __restrict__ out,
                                              const float* __restrict__ W, const float* __restrict__ bias, int l) {
  constexpr int NC = COUT / 64;
  const int d0 = l * NC;
  float acc[NC];
#pragma unroll
  for (int k = 0; k < NC; ++k) acc[k] = bias[d0 + k];
#pragma unroll
  for (int n = 0; n < 8; ++n) {
    const float* xr = in + n * 68;
#pragma unroll 4
    for (int c4 = 0; c4 < 16; ++c4) {
      v4f x4 = *(const v4f*)(xr + 4 * c4);
#pragma unroll
      for (int j = 0; j < 4; ++j) {
        const float* wr = W + ((n * 64) + 4 * c4 + j) * COUT + d0;
#pragma unroll
        for (int k = 0; k < NC; ++k) acc[k] = fmaf(x4[j], wr[k], acc[k]);
      }
    }
  }
#pragma unroll
  for (int k = 0; k < NC; ++k) out[d0 + k] = ACT ? lrelu(acc[k]) : acc[k];
}

template<int CIN, int COUT, bool ACT>
__device__ __forceinline__ void wave_dense(const float* __restrict__ in, float* __restrict__ out,
                                           const float* __restrict__ W, const float* __restrict__ bias, int l) {
  if constexpr (COUT >= 64) {
    constexpr int NC = COUT / 64;
    const int d0 = l * NC;
    float acc[NC];
#pragma unroll
    for (int k = 0; k < NC; ++k) acc[k] = bias[d0 + k];
#pragma unroll 4
    for (int c4 = 0; c4 < CIN / 4; ++c4) {
      v4f x4 = *(const v4f*)(in + 4 * c4);
#pragma unroll
      for (int j = 0; j < 4; ++j) {
        const float* wr = W + (4 * c4 + j) * COUT + d0;
#pragma unroll
        for (int k = 0; k < NC; ++k) acc[k] = fmaf(x4[j], wr[k], acc[k]);
      }
    }
#pragma unroll
    for (int k = 0; k < NC; ++k) out[d0 + k] = ACT ? lrelu(acc[k]) : acc[k];
  } else {
    if (l < COUT) {
      float acc = bias[l];
#pragma unroll 4
      for (int c4 = 0; c4 < CIN / 4; ++c4) {
        v4f x4 = *(const v4f*)(in + 4 * c4);
#pragma unroll
        for (int j = 0; j < 4; ++j) acc = fmaf(x4[j], W[(4 * c4 + j) * COUT + l], acc);
      }
      out[l] = ACT ? lrelu(acc) : acc;
    }
  }
}

__global__ __launch_bounds__(THREADS)
void tail_kernel(const float* __restrict__ emb, const float* __restrict__ state,
    const float* __restrict__ mw1, const float* __restrict__ mb1,
    const float* __restrict__ mw2, const float* __restrict__ mb2,
    const float* __restrict__ mw3, const float* __restrict__ mb3,
    const float* __restrict__ mw4, const float* __restrict__ mb4,
    const float* __restrict__ mdw, const float* __restrict__ mdb,
    const float* __restrict__ sw1, const float* __restrict__ sb1,
    const float* __restrict__ sw2, const float* __restrict__ sb2,
    const float* __restrict__ sw3, const float* __restrict__ sb3,
    const float* __restrict__ sw4, const float* __restrict__ sb4,
    const float* __restrict__ sdw, const float* __restrict__ sdb,
    const float* __restrict__ cw1, const float* __restrict__ cb1,
    const float* __restrict__ cw2, const float* __restrict__ cb2,
    const float* __restrict__ cw3, const float* __restrict__ cb3,
    const float* __restrict__ cw4, const float* __restrict__ cb4,
    float* __restrict__ out)
{
  const int t = threadIdx.x, l = t & 63, w = t >> 6;
  const int sub = w >> 1;
  const int br  = w & 1;
  const int b   = blockIdx.x * 2 + sub;

  __shared__ float M0[2][8 * 132], M1[2][8 * 132];
  __shared__ float S0[2][8 * 132], S1[2][8 * 132];
  __shared__ float sin_[2][8 * 40];
  __shared__ float cat[2][256];

  float* m0 = M0[sub]; float* m1 = M1[sub];
  float* s0 = S0[sub]; float* s1 = S1[sub];

  if (br == 0) {
    const float* esrc = emb + (size_t)b * 1024;
    for (int i = l; i < 256; i += 64) {
      v4f v = *(const v4f*)(esrc + 4 * i);
      int n = (4 * i) >> 7, c = (4 * i) & 127;
      *(v4f*)(m0 + n * 132 + c) = v;
    }
  } else {
    const float* ssrc = state + (size_t)b * (S * SD);
    for (int i = l; i < S * SD; i += 64) sin_[sub][(i / SD) * 40 + (i % SD)] = ssrc[i];
  }
  __syncthreads();

  if (br == 0) wave_conv<128, 128, 132, 132, true>(m0, m1, mw1, mb1, l);
  else         wave_conv<SD,  128,  40, 132, true>(sin_[sub], s0, sw1, sb1, l);
  __syncthreads();
  if (br == 0) wave_conv<128, 64, 132, 68, true>(m1, m0, mw2, mb2, l);
  else         wave_conv<128, 64, 132, 68, true>(s0, s1, sw2, sb2, l);
  __syncthreads();
  if (br == 0) wave_conv<64, 64, 68, 68, true>(m0, m1, mw3, mb3, l);
  else         wave_conv<64, 64, 68, 68, true>(s1, s0, sw3, sb3, l);
  __syncthreads();
  if (br == 0) wave_conv<64, 64, 68, 68, true>(m1, m0, mw4, mb4, l);
  else         wave_conv<64, 64, 68, 68, false>(s0, s1, sw4, sb4, l);
  __syncthreads();
  if (br == 0) wave_dense512<128, false>(m0, cat[sub],       mdw, mdb, l);
  else         wave_dense512<128, false>(s1, cat[sub] + 128, sdw, sdb, l);
  __syncthreads();

  float* h1 = m1; float* h2 = m1 + 128; float* h3 = m1 + 192;
  if (br == 0) wave_dense<256, 128, true>(cat[sub], h1, cw1, cb1, l);
  __syncthreads();
  if (br == 0) wave_dense<128, 64, true>(h1, h2, cw2, cb2, l);
  __syncthreads();
  if (br == 0) wave_dense<64, 32, true>(h2, h3, cw3, cb3, l);
  __syncthreads();
  if (br == 0 && l < 4) {
    float acc = cb4[l];
#pragma unroll
    for (int c = 0; c < 32; ++c) acc = fmaf(h3[c], cw4[c * 4 + l], acc);
    out[(size_t)b * 4 + l] = (l == 0) ? 21.f / (1.f + expf(-acc)) : 6.f * tanhf(acc);
  }
}

extern "C" void kernel_launch(void* const* d_in, const int* in_sizes, int n_in,
                              void* d_out, int out_size, void* d_ws, size_t ws_size,
                              hipStream_t stream) {
  const float* p[44];
  for (int i = 0; i < 44; ++i) p[i] = (const float*)d_in[i];

  float* emb = (float*)d_ws;                                        // 4 MB
  unsigned short* w2f = (unsigned short*)((char*)d_ws + 4194304);   // 4 KB
  unsigned short* w3f = w2f + 4 * 64 * 8;                           // 16 KB

  prep_weights<<<4, 256, 0, stream>>>(p[6], p[10], w2f, w3f);

  pointnet_kernel<<<1024 * S, THREADS, 0, stream>>>(
      p[0],
      p[2], p[4], p[5],
      w2f, p[8], p[9],
      w3f, p[12], p[13],
      p[14], p[15],
      emb);

  tail_kernel<<<512, THREADS, 0, stream>>>(
      emb, p[1],
      p[16], p[17], p[18], p[19], p[20], p[21], p[22], p[23], p[24], p[25],
      p[26], p[27], p[28], p[29], p[30], p[31], p[32], p[33], p[34], p[35],
      p[36], p[37], p[38], p[39], p[40], p[41], p[42], p[43],
      (float*)d_out);
}

// Round 5
// 97.691 us; speedup vs baseline: 5.0650x; 2.0076x over previous
//
#include <hip/hip_runtime.h>
#include <math.h>

#define THREADS 256

constexpr int S   = 8;
constexpr int NPT = 64;
constexpr int SD  = 36;
constexpr float EPS = 1e-5f;

typedef float v4f __attribute__((ext_vector_type(4)));
typedef __attribute__((ext_vector_type(8))) short bf8;   // 8 bf16 (4 VGPR)
typedef __attribute__((ext_vector_type(4))) float f4;    // MFMA accumulator

__device__ __forceinline__ float lrelu(float x) { return x > 0.f ? x : 0.01f * x; }

// float -> bf16 round-to-nearest-even
__device__ __forceinline__ unsigned short f2bf(float x) {
  union { float f; unsigned u; } v; v.f = x;
  unsigned r = v.u + 0x7FFFu + ((v.u >> 16) & 1u);
  return (unsigned short)(r >> 16);
}

// ==================== fragment packing (one-time prep) ====================
// B-fragment: frag f = kt*NT + nt; lane l holds n = nt*16 + (l&15),
// k = kt*32 + (l>>4)*8 + j, j=0..7. TS>0: 2-tap conv weight [2][CIN][N] with
// tap stride TS (zero-pad c >= CIN). TS==0: flat [K][N].
__device__ __forceinline__ void pack_frag(const float* __restrict__ src, unsigned short* __restrict__ dst,
                                          int slot, int NT, int TS, int CIN, int N) {
  const int f = slot >> 6, l = slot & 63;
  const int nt = f % NT, kt = f / NT;
  const int n = nt * 16 + (l & 15), g = (l >> 4);
  unsigned short* d = dst + (size_t)f * 512 + l * 8;
#pragma unroll
  for (int j = 0; j < 8; ++j) {
    int k = kt * 32 + g * 8 + j;
    float v;
    if (TS > 0) { int tap = k / TS, c = k - tap * TS; v = (c < CIN) ? src[(tap * CIN + c) * N + n] : 0.f; }
    else        v = src[k * N + n];
    d[j] = f2bf(v);
  }
}

// fragment-region offsets in u16 units (frag = 512 u16)
#define WOFF_PNW2 0
#define WOFF_PNW3 2048
#define WOFF_MW1  10240
#define WOFF_MW2  43008
#define WOFF_MW3  59392
#define WOFF_MW4  67584
#define WOFF_MDW  75776
#define WOFF_SW1  141312
#define WOFF_SW2  153600
#define WOFF_SW3  169984
#define WOFF_SW4  178176
#define WOFF_SDW  186368
// total 492 frags = 251904 u16 = 503808 B

__global__ void prep_weights(const float* __restrict__ pw2, const float* __restrict__ pw3,
    const float* __restrict__ mw1, const float* __restrict__ mw2, const float* __restrict__ mw3,
    const float* __restrict__ mw4, const float* __restrict__ mdw,
    const float* __restrict__ sw1, const float* __restrict__ sw2, const float* __restrict__ sw3,
    const float* __restrict__ sw4, const float* __restrict__ sdw,
    unsigned short* __restrict__ wf) {
  const int slot = blockIdx.x * 256 + threadIdx.x;
  if      (slot <   256) pack_frag(pw2, wf + WOFF_PNW2, slot,          4,   0,   0,  64);
  else if (slot <  1280) pack_frag(pw3, wf + WOFF_PNW3, slot - 256,    8,   0,   0, 128);
  else if (slot <  5376) pack_frag(mw1, wf + WOFF_MW1,  slot - 1280,   8, 128, 128, 128);
  else if (slot <  7424) pack_frag(mw2, wf + WOFF_MW2,  slot - 5376,   4, 128, 128,  64);
  else if (slot <  8448) pack_frag(mw3, wf + WOFF_MW3,  slot - 7424,   4,  64,  64,  64);
  else if (slot <  9472) pack_frag(mw4, wf + WOFF_MW4,  slot - 8448,   4,  64,  64,  64);
  else if (slot < 17664) pack_frag(mdw, wf + WOFF_MDW,  slot - 9472,   8,   0,   0, 128);
  else if (slot < 19200) pack_frag(sw1, wf + WOFF_SW1,  slot - 17664,  8,  48,  36, 128);
  else if (slot < 21248) pack_frag(sw2, wf + WOFF_SW2,  slot - 19200,  4, 128, 128,  64);
  else if (slot < 22272) pack_frag(sw3, wf + WOFF_SW3,  slot - 21248,  4,  64,  64,  64);
  else if (slot < 23296) pack_frag(sw4, wf + WOFF_SW4,  slot - 22272,  4,  64,  64,  64);
  else if (slot < 31488) pack_frag(sdw, wf + WOFF_SDW,  slot - 23296,  8,   0,   0, 128);
}

// ==================== kernel 1: pointnet (unchanged structure, bf16 emb out) ====================
template<int CIN, int COUT, int SPI, int SPO, int TN, int TD>
__device__ __forceinline__ void mm_sca(const float* __restrict__ in, float* __restrict__ out,
                                       const float* __restrict__ W, int t) {
  constexpr int ND = COUT / TD;
  static_assert((NPT / TN) * ND == THREADS, "tile");
  const int n0 = (t / ND) * TN, d0 = (t % ND) * TD;
  float acc[TN][TD]{};
#pragma unroll
  for (int c = 0; c < CIN; ++c) {
    float xv[TN], wv[TD];
#pragma unroll
    for (int i = 0; i < TN; ++i) xv[i] = in[(n0 + i) * SPI + c];
#pragma unroll
    for (int j = 0; j < TD; ++j) wv[j] = W[c * COUT + d0 + j];
#pragma unroll
    for (int i = 0; i < TN; ++i)
#pragma unroll
      for (int j = 0; j < TD; ++j) acc[i][j] = fmaf(xv[i], wv[j], acc[i][j]);
  }
#pragma unroll
  for (int i = 0; i < TN; ++i)
#pragma unroll
    for (int j = 0; j < TD; ++j) out[(n0 + i) * SPO + d0 + j] = acc[i][j];
}

__global__ __launch_bounds__(THREADS)
void pointnet_kernel(const float* __restrict__ fts,
    const float* __restrict__ pw1, const float* __restrict__ pg1, const float* __restrict__ pbe1,
    const unsigned short* __restrict__ w2f, const float* __restrict__ pg2, const float* __restrict__ pbe2,
    const unsigned short* __restrict__ w3f, const float* __restrict__ pg3, const float* __restrict__ pbe3,
    const float* __restrict__ pw4, const float* __restrict__ pb4,
    unsigned short* __restrict__ emb)
{
  const int p = blockIdx.x;            // b*S + s
  const int t = threadIdx.x;
  const int l = t & 63, w = t >> 6;
  const int g = l >> 4, lc = l & 15;

  __shared__ float xin[320];
  __shared__ float x1[64 * 36];
  __shared__ unsigned short x1b[64 * 40];
  __shared__ unsigned short x2b[64 * 72];
  __shared__ float ps[256], pss[256];
  __shared__ float aA[32], bA[32];
  __shared__ float xbar[128];

  { const float* src = fts + (size_t)p * 320;
    for (int i = t; i < 320; i += THREADS) xin[i] = src[i]; }
  __syncthreads();

  mm_sca<5, 32, 5, 36, 4, 2>(xin, x1, pw1, t);
  __syncthreads();

  {
    const int c = t & 31, gr = t >> 5;
    float s = 0.f, ss = 0.f;
#pragma unroll
    for (int k = 0; k < 8; ++k) { float v = x1[(gr + 8 * k) * 36 + c]; s += v; ss = fmaf(v, v, ss); }
    ps[t] = s; pss[t] = ss;
    __syncthreads();
    if (t < 32) {
      float S1 = 0.f, S2 = 0.f;
#pragma unroll
      for (int h = 0; h < 8; ++h) { S1 += ps[h * 32 + t]; S2 += pss[h * 32 + t]; }
      float mu  = S1 * (1.f / NPT);
      float inv = rsqrtf(S2 * (1.f / NPT) - mu * mu + EPS);
      float a = inv * pg1[t];
      aA[t] = a; bA[t] = fmaf(-mu, a, pbe1[t]);
    }
    __syncthreads();
    const float a = aA[c], bb = bA[c];
#pragma unroll
    for (int k = 0; k < 8; ++k) {
      int r = gr + 8 * k;
      x1b[r * 40 + c] = f2bf(lrelu(fmaf(x1[r * 36 + c], a, bb)));
    }
  }
  __syncthreads();

  // L2 MFMA
  f4 c2[4];
#pragma unroll
  for (int mt = 0; mt < 4; ++mt) c2[mt] = f4{0.f, 0.f, 0.f, 0.f};
  {
    bf8 bfrag = *(const bf8*)(w2f + ((size_t)w * 64 + l) * 8);
#pragma unroll
    for (int mt = 0; mt < 4; ++mt) {
      bf8 afrag = *(const bf8*)(x1b + (mt * 16 + lc) * 40 + g * 8);
      c2[mt] = __builtin_amdgcn_mfma_f32_16x16x32_bf16(afrag, bfrag, c2[mt], 0, 0, 0);
    }
  }
  {
    float s = 0.f, q = 0.f;
#pragma unroll
    for (int mt = 0; mt < 4; ++mt)
#pragma unroll
      for (int r = 0; r < 4; ++r) { float v = c2[mt][r]; s += v; q = fmaf(v, v, q); }
    s += __shfl_xor(s, 16, 64); s += __shfl_xor(s, 32, 64);
    q += __shfl_xor(q, 16, 64); q += __shfl_xor(q, 32, 64);
    const int ch = w * 16 + lc;
    float mu  = s * (1.f / NPT);
    float inv = rsqrtf(q * (1.f / NPT) - mu * mu + EPS);
    float a = inv * pg2[ch];
    float bb = fmaf(-mu, a, pbe2[ch]);
#pragma unroll
    for (int mt = 0; mt < 4; ++mt)
#pragma unroll
      for (int r = 0; r < 4; ++r) {
        int row = mt * 16 + g * 4 + r;
        x2b[row * 72 + ch] = f2bf(lrelu(fmaf(c2[mt][r], a, bb)));
      }
  }
  __syncthreads();

  // L3 MFMA
  f4 c3[4][2];
#pragma unroll
  for (int mt = 0; mt < 4; ++mt)
#pragma unroll
    for (int n = 0; n < 2; ++n) c3[mt][n] = f4{0.f, 0.f, 0.f, 0.f};
  bf8 bf3[2][2];
#pragma unroll
  for (int ntl = 0; ntl < 2; ++ntl)
#pragma unroll
    for (int kt = 0; kt < 2; ++kt)
      bf3[ntl][kt] = *(const bf8*)(w3f + ((size_t)(kt * 8 + (2 * w + ntl)) * 64 + l) * 8);
#pragma unroll
  for (int mt = 0; mt < 4; ++mt)
#pragma unroll
    for (int kt = 0; kt < 2; ++kt) {
      bf8 afrag = *(const bf8*)(x2b + (mt * 16 + lc) * 72 + kt * 32 + g * 8);
#pragma unroll
      for (int ntl = 0; ntl < 2; ++ntl)
        c3[mt][ntl] = __builtin_amdgcn_mfma_f32_16x16x32_bf16(afrag, bf3[ntl][kt], c3[mt][ntl], 0, 0, 0);
    }

#pragma unroll
  for (int ntl = 0; ntl < 2; ++ntl) {
    float s = 0.f, q = 0.f;
#pragma unroll
    for (int mt = 0; mt < 4; ++mt)
#pragma unroll
      for (int r = 0; r < 4; ++r) { float v = c3[mt][ntl][r]; s += v; q = fmaf(v, v, q); }
    s += __shfl_xor(s, 16, 64); s += __shfl_xor(s, 32, 64);
    q += __shfl_xor(q, 16, 64); q += __shfl_xor(q, 32, 64);
    const int ch = w * 32 + ntl * 16 + lc;
    float mu  = s * (1.f / NPT);
    float inv = rsqrtf(q * (1.f / NPT) - mu * mu + EPS);
    float a = inv * pg3[ch];
    float bb = fmaf(-mu, a, pbe3[ch]);
    float m = 0.f;
#pragma unroll
    for (int mt = 0; mt < 4; ++mt)
#pragma unroll
      for (int r = 0; r < 4; ++r) m += lrelu(fmaf(c3[mt][ntl][r], a, bb));
    m += __shfl_xor(m, 16, 64); m += __shfl_xor(m, 32, 64);
    if (g == 0) xbar[ch] = m * (1.f / NPT);
  }
  __syncthreads();

  {
    const int d = t & 127, h = t >> 7;
    float a = 0.f;
#pragma unroll 8
    for (int c = h * 64; c < h * 64 + 64; ++c) a = fmaf(xbar[c], pw4[c * 128 + d], a);
    ps[t] = a;
  }
  __syncthreads();
  if (t < 128) emb[(size_t)p * 128 + t] = f2bf(ps[t] + ps[t + 128] + pb4[t]);
}

// ==================== kernel 2: MFMA tail, G=8 b's per block ====================
// A layout in LDS: [b_loc][9][SP] bf16, row 8 = zeros (2-tap overflow).
// Wave w owns m-tile w = rows w*16..w*16+15 = b's {2w, 2w+1}.
template<int KT, int NT, int TS, int SPI, int SPO, bool ACT>
__device__ __forceinline__ void mfma_conv(const unsigned short* __restrict__ xin,
    unsigned short* __restrict__ xout, const unsigned short* __restrict__ wfr,
    const float* __restrict__ bias, int w, int l) {
  const int g = l >> 4, lc = l & 15;
  const int arow = w * 16 + lc, abl = arow >> 3, an = arow & 7;
  f4 acc[NT];
#pragma unroll
  for (int nt = 0; nt < NT; ++nt) acc[nt] = f4{0.f, 0.f, 0.f, 0.f};
#pragma unroll
  for (int kt = 0; kt < KT; ++kt) {
    const int k0 = kt * 32 + g * 8;
    const int tap = k0 / TS, c = k0 - tap * TS;
    bf8 a = *(const bf8*)(xin + (abl * 9 + an + tap) * SPI + c);
#pragma unroll
    for (int nt = 0; nt < NT; ++nt) {
      bf8 b = *(const bf8*)(wfr + ((size_t)(kt * NT + nt) * 64 + l) * 8);
      acc[nt] = __builtin_amdgcn_mfma_f32_16x16x32_bf16(a, b, acc[nt], 0, 0, 0);
    }
  }
  const int orow0 = w * 16 + g * 4;
#pragma unroll
  for (int nt = 0; nt < NT; ++nt) {
    const float bv = bias[nt * 16 + lc];
#pragma unroll
    for (int r = 0; r < 4; ++r) {
      const int rr = orow0 + r, obl = rr >> 3, on = rr & 7;
      float v = acc[nt][r] + bv;
      if (ACT) v = lrelu(v);
      xout[(obl * 9 + on) * SPO + nt * 16 + lc] = f2bf(v);
    }
  }
}

// dense 512->128 over [8 b][8 n][64 ch] (K-split over 4 waves, partials to LDS)
__device__ __forceinline__ void mfma_dense512(const unsigned short* __restrict__ xin,
    float* __restrict__ P, const unsigned short* __restrict__ wfr, int w, int l) {
  const int g = l >> 4, lc = l & 15;
  const int bl = lc & 7;                 // rows 8-15 duplicate rows 0-7
  f4 acc[8];
#pragma unroll
  for (int nt = 0; nt < 8; ++nt) acc[nt] = f4{0.f, 0.f, 0.f, 0.f};
#pragma unroll
  for (int kt2 = 0; kt2 < 4; ++kt2) {
    const int kt = w * 4 + kt2;
    const int k0 = kt * 32 + g * 8;
    const int n = k0 >> 6, c = k0 & 63;
    bf8 a = *(const bf8*)(xin + (bl * 9 + n) * 72 + c);
#pragma unroll
    for (int nt = 0; nt < 8; ++nt) {
      bf8 b = *(const bf8*)(wfr + ((size_t)(kt * 8 + nt) * 64 + l) * 8);
      acc[nt] = __builtin_amdgcn_mfma_f32_16x16x32_bf16(a, b, acc[nt], 0, 0, 0);
    }
  }
  if (g < 2) {
#pragma unroll
    for (int nt = 0; nt < 8; ++nt)
#pragma unroll
      for (int r = 0; r < 4; ++r) {
        const int rr = g * 4 + r;       // 0..7
        P[(w * 8 + rr) * 128 + nt * 16 + lc] = acc[nt][r];
      }
  }
}

__global__ __launch_bounds__(THREADS)
void tail_mfma_kernel(const unsigned short* __restrict__ emb, const float* __restrict__ state,
    const unsigned short* __restrict__ wf,
    const float* __restrict__ mb1, const float* __restrict__ mb2, const float* __restrict__ mb3,
    const float* __restrict__ mb4, const float* __restrict__ mdb,
    const float* __restrict__ sb1, const float* __restrict__ sb2, const float* __restrict__ sb3,
    const float* __restrict__ sb4, const float* __restrict__ sdb,
    float* __restrict__ femb, float* __restrict__ semb)
{
  const int t = threadIdx.x, l = t & 63, w = t >> 6;
  const bool merge = blockIdx.x < 128;
  const int bg = merge ? blockIdx.x : blockIdx.x - 128;

  __shared__ unsigned short lds[24768];           // 49.5 KB
  unsigned short* BufX = lds;                     // [8][9][136] xin / L3-out [8][9][72] / partials
  unsigned short* BufY = lds + 9792;              // L1-out [8][9][136] / L4-out [8][9][72]
  unsigned short* BufZ = lds + 19584;             // L2-out [8][9][72]

  // zero: BufX fully; BufY row-8 (stride 136); BufZ row-8 (stride 72)
  { unsigned* z = (unsigned*)BufX; for (int i = t; i < 4896; i += THREADS) z[i] = 0; }
  for (int i = t; i < 8 * 136; i += THREADS) BufY[((i / 136) * 9 + 8) * 136 + (i % 136)] = 0;
  for (int i = t; i < 8 * 72;  i += THREADS) BufZ[((i / 72)  * 9 + 8) * 72  + (i % 72)]  = 0;

  if (merge) {
    for (int i = t; i < 1024; i += THREADS) {     // 8b x 8n x 16 chunks of 8 bf16
      int bl = i >> 7, rem = i & 127, n = rem >> 4, sl = rem & 15;
      bf8 v = *(const bf8*)(emb + (size_t)((bg * 8 + bl) * 8 + n) * 128 + sl * 8);
      *(bf8*)(BufX + (bl * 9 + n) * 136 + sl * 8) = v;
    }
  } else {
    for (int i = t; i < 2304; i += THREADS) {     // 8b x 8n x 36
      int bl = i / 288, rem = i % 288, n = rem / 36, c = rem % 36;
      BufX[(bl * 9 + n) * 48 + c] = f2bf(state[((size_t)(bg * 8 + bl) * 8 + n) * 36 + c]);
    }
  }
  __syncthreads();

  if (merge) mfma_conv<8, 8, 128, 136, 136, true>(BufX, BufY, wf + WOFF_MW1, mb1, w, l);
  else       mfma_conv<3, 8,  48,  48, 136, true>(BufX, BufY, wf + WOFF_SW1, sb1, w, l);
  __syncthreads();
  if (merge) mfma_conv<8, 4, 128, 136, 72, true>(BufY, BufZ, wf + WOFF_MW2, mb2, w, l);
  else       mfma_conv<8, 4, 128, 136, 72, true>(BufY, BufZ, wf + WOFF_SW2, sb2, w, l);
  // BufX is dead (conv1 reads done 1 barrier ago); set up L3's zero row-8 (stride 72)
  __syncthreads();
  for (int i = t; i < 8 * 72; i += THREADS) BufX[((i / 72) * 9 + 8) * 72 + (i % 72)] = 0;
  __syncthreads();
  if (merge) mfma_conv<4, 4, 64, 72, 72, true>(BufZ, BufX, wf + WOFF_MW3, mb3, w, l);
  else       mfma_conv<4, 4, 64, 72, 72, true>(BufZ, BufX, wf + WOFF_SW3, sb3, w, l);
  __syncthreads();
  if (merge) mfma_conv<4, 4, 64, 72, 72, true >(BufX, BufY, wf + WOFF_MW4, mb4, w, l);
  else       mfma_conv<4, 4, 64, 72, 72, false>(BufX, BufY, wf + WOFF_SW4, sb4, w, l);
  __syncthreads();

  float* P = (float*)lds;                         // 16 KB partials (BufX region, dead)
  mfma_dense512(BufY, P, wf + (merge ? WOFF_MDW : WOFF_SDW), w, l);
  __syncthreads();

  const float* bias = merge ? mdb : sdb;
  float* outg = (merge ? femb : semb) + (size_t)bg * 1024;
  for (int i = t; i < 1024; i += THREADS) {
    int ch = i & 127, b = i >> 7;
    outg[i] = bias[ch] + P[(0 * 8 + b) * 128 + ch] + P[(1 * 8 + b) * 128 + ch]
                       + P[(2 * 8 + b) * 128 + ch] + P[(3 * 8 + b) * 128 + ch];
  }
}

// ==================== kernel 3: control head, one wave per b ====================
template<int CIN, int COUT, bool ACT>
__device__ __forceinline__ void wave_dense(const float* __restrict__ in, float* __restrict__ out,
                                           const float* __restrict__ W, const float* __restrict__ bias, int l) {
  if constexpr (COUT >= 64) {
    constexpr int NC = COUT / 64;
    const int d0 = l * NC;
    float acc[NC];
#pragma unroll
    for (int k = 0; k < NC; ++k) acc[k] = bias[d0 + k];
#pragma unroll 4
    for (int c4 = 0; c4 < CIN / 4; ++c4) {
      v4f x4 = *(const v4f*)(in + 4 * c4);
#pragma unroll
      for (int j = 0; j < 4; ++j) {
        const float* wr = W + (4 * c4 + j) * COUT + d0;
#pragma unroll
        for (int k = 0; k < NC; ++k) acc[k] = fmaf(x4[j], wr[k], acc[k]);
      }
    }
#pragma unroll
    for (int k = 0; k < NC; ++k) out[d0 + k] = ACT ? lrelu(acc[k]) : acc[k];
  } else {
    if (l < COUT) {
      float acc = bias[l];
#pragma unroll 4
      for (int c4 = 0; c4 < CIN / 4; ++c4) {
        v4f x4 = *(const v4f*)(in + 4 * c4);
#pragma unroll
        for (int j = 0; j < 4; ++j) acc = fmaf(x4[j], W[(4 * c4 + j) * COUT + l], acc);
      }
      out[l] = ACT ? lrelu(acc) : acc;
    }
  }
}

__global__ __launch_bounds__(THREADS)
void head_kernel(const float* __restrict__ femb, const float* __restrict__ semb,
    const float* __restrict__ cw1, const float* __restrict__ cb1,
    const float* __restrict__ cw2, const float* __restrict__ cb2,
    const float* __restrict__ cw3, const float* __restrict__ cb3,
    const float* __restrict__ cw4, const float* __restrict__ cb4,
    float* __restrict__ out)
{
  const int t = threadIdx.x, l = t & 63, w = t >> 6;
  const int b = blockIdx.x * 4 + w;
  __shared__ float cat[4][256];
  __shared__ float hb[4][232];    // h1 128 | h2 64 | h3 32 (+pad)

  cat[w][l]       = femb[(size_t)b * 128 + l];
  cat[w][64 + l]  = femb[(size_t)b * 128 + 64 + l];
  cat[w][128 + l] = semb[(size_t)b * 128 + l];
  cat[w][192 + l] = semb[(size_t)b * 128 + 64 + l];
  __syncthreads();
  wave_dense<256, 128, true>(cat[w], hb[w], cw1, cb1, l);
  __syncthreads();
  wave_dense<128, 64, true>(hb[w], hb[w] + 128, cw2, cb2, l);
  __syncthreads();
  wave_dense<64, 32, true>(hb[w] + 128, hb[w] + 192, cw3, cb3, l);
  __syncthreads();
  if (l < 4) {
    float acc = cb4[l];
#pragma unroll
    for (int c = 0; c < 32; ++c) acc = fmaf(hb[w][192 + c], cw4[c * 4 + l], acc);
    out[(size_t)b * 4 + l] = (l == 0) ? 21.f / (1.f + expf(-acc)) : 6.f * tanhf(acc);
  }
}

extern "C" void kernel_launch(void* const* d_in, const int* in_sizes, int n_in,
                              void* d_out, int out_size, void* d_ws, size_t ws_size,
                              hipStream_t stream) {
  const float* p[44];
  for (int i = 0; i < 44; ++i) p[i] = (const float*)d_in[i];

  unsigned short* emb_bf = (unsigned short*)d_ws;                      // 2 MB
  float* femb = (float*)((char*)d_ws + 2097152);                       // 512 KB
  float* semb = (float*)((char*)d_ws + 2621440);                       // 512 KB
  unsigned short* wf = (unsigned short*)((char*)d_ws + 3145728);       // 504 KB

  prep_weights<<<123, THREADS, 0, stream>>>(
      p[6], p[10],
      p[16], p[18], p[20], p[22], p[24],
      p[26], p[28], p[30], p[32], p[34],
      wf);

  pointnet_kernel<<<1024 * S, THREADS, 0, stream>>>(
      p[0],
      p[2], p[4], p[5],
      wf + WOFF_PNW2, p[8], p[9],
      wf + WOFF_PNW3, p[12], p[13],
      p[14], p[15],
      emb_bf);

  tail_mfma_kernel<<<256, THREADS, 0, stream>>>(
      emb_bf, p[1], wf,
      p[17], p[19], p[21], p[23], p[25],
      p[27], p[29], p[31], p[33], p[35],
      femb, semb);

  head_kernel<<<256, THREADS, 0, stream>>>(
      femb, semb,
      p[36], p[37], p[38], p[39], p[40], p[41], p[42], p[43],
      (float*)d_out);
}

// Round 6
// 95.930 us; speedup vs baseline: 5.1580x; 1.0184x over previous
//
#include <hip/hip_runtime.h>
#include <math.h>

#define THREADS 256

constexpr int S   = 8;
constexpr int NPT = 64;
constexpr int SD  = 36;
constexpr float EPS = 1e-5f;

typedef float v4f __attribute__((ext_vector_type(4)));
typedef __attribute__((ext_vector_type(8))) short bf8;   // 8 bf16 (4 VGPR)
typedef __attribute__((ext_vector_type(4))) float f4;    // MFMA accumulator

__device__ __forceinline__ float lrelu(float x) { return x > 0.f ? x : 0.01f * x; }

// float -> bf16 round-to-nearest-even
__device__ __forceinline__ unsigned short f2bf(float x) {
  union { float f; unsigned u; } v; v.f = x;
  unsigned r = v.u + 0x7FFFu + ((v.u >> 16) & 1u);
  return (unsigned short)(r >> 16);
}

// ==================== fragment packing (one-time prep) ====================
// B-fragment: frag f = kt*NT + nt; lane l holds n = nt*16 + (l&15),
// k = kt*32 + (l>>4)*8 + j, j=0..7. TS>0: 2-tap conv weight [2][CIN][N] with
// tap stride TS (zero-pad c >= CIN). TS==0: flat [K][N].
__device__ __forceinline__ void pack_frag(const float* __restrict__ src, unsigned short* __restrict__ dst,
                                          int slot, int NT, int TS, int CIN, int N) {
  const int f = slot >> 6, l = slot & 63;
  const int nt = f % NT, kt = f / NT;
  const int n = nt * 16 + (l & 15), g = (l >> 4);
  unsigned short* d = dst + (size_t)f * 512 + l * 8;
#pragma unroll
  for (int j = 0; j < 8; ++j) {
    int k = kt * 32 + g * 8 + j;
    float v;
    if (TS > 0) { int tap = k / TS, c = k - tap * TS; v = (c < CIN) ? src[(tap * CIN + c) * N + n] : 0.f; }
    else        v = src[k * N + n];
    d[j] = f2bf(v);
  }
}

// fragment-region offsets in u16 units (frag = 512 u16)
#define WOFF_PNW2 0
#define WOFF_PNW3 2048
#define WOFF_MW1  10240
#define WOFF_MW2  43008
#define WOFF_MW3  59392
#define WOFF_MW4  67584
#define WOFF_MDW  75776
#define WOFF_SW1  141312
#define WOFF_SW2  153600
#define WOFF_SW3  169984
#define WOFF_SW4  178176
#define WOFF_SDW  186368
// total 492 frags = 251904 u16 = 503808 B

__global__ void prep_weights(const float* __restrict__ pw2, const float* __restrict__ pw3,
    const float* __restrict__ mw1, const float* __restrict__ mw2, const float* __restrict__ mw3,
    const float* __restrict__ mw4, const float* __restrict__ mdw,
    const float* __restrict__ sw1, const float* __restrict__ sw2, const float* __restrict__ sw3,
    const float* __restrict__ sw4, const float* __restrict__ sdw,
    unsigned short* __restrict__ wf) {
  const int slot = blockIdx.x * 256 + threadIdx.x;
  if      (slot <   256) pack_frag(pw2, wf + WOFF_PNW2, slot,          4,   0,   0,  64);
  else if (slot <  1280) pack_frag(pw3, wf + WOFF_PNW3, slot - 256,    8,   0,   0, 128);
  else if (slot <  5376) pack_frag(mw1, wf + WOFF_MW1,  slot - 1280,   8, 128, 128, 128);
  else if (slot <  7424) pack_frag(mw2, wf + WOFF_MW2,  slot - 5376,   4, 128, 128,  64);
  else if (slot <  8448) pack_frag(mw3, wf + WOFF_MW3,  slot - 7424,   4,  64,  64,  64);
  else if (slot <  9472) pack_frag(mw4, wf + WOFF_MW4,  slot - 8448,   4,  64,  64,  64);
  else if (slot < 17664) pack_frag(mdw, wf + WOFF_MDW,  slot - 9472,   8,   0,   0, 128);
  else if (slot < 19200) pack_frag(sw1, wf + WOFF_SW1,  slot - 17664,  8,  48,  36, 128);
  else if (slot < 21248) pack_frag(sw2, wf + WOFF_SW2,  slot - 19200,  4, 128, 128,  64);
  else if (slot < 22272) pack_frag(sw3, wf + WOFF_SW3,  slot - 21248,  4,  64,  64,  64);
  else if (slot < 23296) pack_frag(sw4, wf + WOFF_SW4,  slot - 22272,  4,  64,  64,  64);
  else if (slot < 31488) pack_frag(sdw, wf + WOFF_SDW,  slot - 23296,  8,   0,   0, 128);
}

// ==================== kernel 1: pointnet (unchanged structure, bf16 emb out) ====================
template<int CIN, int COUT, int SPI, int SPO, int TN, int TD>
__device__ __forceinline__ void mm_sca(const float* __restrict__ in, float* __restrict__ out,
                                       const float* __restrict__ W, int t) {
  constexpr int ND = COUT / TD;
  static_assert((NPT / TN) * ND == THREADS, "tile");
  const int n0 = (t / ND) * TN, d0 = (t % ND) * TD;
  float acc[TN][TD]{};
#pragma unroll
  for (int c = 0; c < CIN; ++c) {
    float xv[TN], wv[TD];
#pragma unroll
    for (int i = 0; i < TN; ++i) xv[i] = in[(n0 + i) * SPI + c];
#pragma unroll
    for (int j = 0; j < TD; ++j) wv[j] = W[c * COUT + d0 + j];
#pragma unroll
    for (int i = 0; i < TN; ++i)
#pragma unroll
      for (int j = 0; j < TD; ++j) acc[i][j] = fmaf(xv[i], wv[j], acc[i][j]);
  }
#pragma unroll
  for (int i = 0; i < TN; ++i)
#pragma unroll
    for (int j = 0; j < TD; ++j) out[(n0 + i) * SPO + d0 + j] = acc[i][j];
}

__global__ __launch_bounds__(THREADS)
void pointnet_kernel(const float* __restrict__ fts,
    const float* __restrict__ pw1, const float* __restrict__ pg1, const float* __restrict__ pbe1,
    const unsigned short* __restrict__ w2f, const float* __restrict__ pg2, const float* __restrict__ pbe2,
    const unsigned short* __restrict__ w3f, const float* __restrict__ pg3, const float* __restrict__ pbe3,
    const float* __restrict__ pw4, const float* __restrict__ pb4,
    unsigned short* __restrict__ emb)
{
  const int p = blockIdx.x;            // b*S + s
  const int t = threadIdx.x;
  const int l = t & 63, w = t >> 6;
  const int g = l >> 4, lc = l & 15;

  __shared__ float xin[320];
  __shared__ float x1[64 * 36];
  __shared__ unsigned short x1b[64 * 40];
  __shared__ unsigned short x2b[64 * 72];
  __shared__ float ps[256], pss[256];
  __shared__ float aA[32], bA[32];
  __shared__ float xbar[128];

  { const float* src = fts + (size_t)p * 320;
    for (int i = t; i < 320; i += THREADS) xin[i] = src[i]; }
  __syncthreads();

  mm_sca<5, 32, 5, 36, 4, 2>(xin, x1, pw1, t);
  __syncthreads();

  {
    const int c = t & 31, gr = t >> 5;
    float s = 0.f, ss = 0.f;
#pragma unroll
    for (int k = 0; k < 8; ++k) { float v = x1[(gr + 8 * k) * 36 + c]; s += v; ss = fmaf(v, v, ss); }
    ps[t] = s; pss[t] = ss;
    __syncthreads();
    if (t < 32) {
      float S1 = 0.f, S2 = 0.f;
#pragma unroll
      for (int h = 0; h < 8; ++h) { S1 += ps[h * 32 + t]; S2 += pss[h * 32 + t]; }
      float mu  = S1 * (1.f / NPT);
      float inv = rsqrtf(S2 * (1.f / NPT) - mu * mu + EPS);
      float a = inv * pg1[t];
      aA[t] = a; bA[t] = fmaf(-mu, a, pbe1[t]);
    }
    __syncthreads();
    const float a = aA[c], bb = bA[c];
#pragma unroll
    for (int k = 0; k < 8; ++k) {
      int r = gr + 8 * k;
      x1b[r * 40 + c] = f2bf(lrelu(fmaf(x1[r * 36 + c], a, bb)));
    }
  }
  __syncthreads();

  // L2 MFMA
  f4 c2[4];
#pragma unroll
  for (int mt = 0; mt < 4; ++mt) c2[mt] = f4{0.f, 0.f, 0.f, 0.f};
  {
    bf8 bfrag = *(const bf8*)(w2f + ((size_t)w * 64 + l) * 8);
#pragma unroll
    for (int mt = 0; mt < 4; ++mt) {
      bf8 afrag = *(const bf8*)(x1b + (mt * 16 + lc) * 40 + g * 8);
      c2[mt] = __builtin_amdgcn_mfma_f32_16x16x32_bf16(afrag, bfrag, c2[mt], 0, 0, 0);
    }
  }
  {
    float s = 0.f, q = 0.f;
#pragma unroll
    for (int mt = 0; mt < 4; ++mt)
#pragma unroll
      for (int r = 0; r < 4; ++r) { float v = c2[mt][r]; s += v; q = fmaf(v, v, q); }
    s += __shfl_xor(s, 16, 64); s += __shfl_xor(s, 32, 64);
    q += __shfl_xor(q, 16, 64); q += __shfl_xor(q, 32, 64);
    const int ch = w * 16 + lc;
    float mu  = s * (1.f / NPT);
    float inv = rsqrtf(q * (1.f / NPT) - mu * mu + EPS);
    float a = inv * pg2[ch];
    float bb = fmaf(-mu, a, pbe2[ch]);
#pragma unroll
    for (int mt = 0; mt < 4; ++mt)
#pragma unroll
      for (int r = 0; r < 4; ++r) {
        int row = mt * 16 + g * 4 + r;
        x2b[row * 72 + ch] = f2bf(lrelu(fmaf(c2[mt][r], a, bb)));
      }
  }
  __syncthreads();

  // L3 MFMA
  f4 c3[4][2];
#pragma unroll
  for (int mt = 0; mt < 4; ++mt)
#pragma unroll
    for (int n = 0; n < 2; ++n) c3[mt][n] = f4{0.f, 0.f, 0.f, 0.f};
  bf8 bf3[2][2];
#pragma unroll
  for (int ntl = 0; ntl < 2; ++ntl)
#pragma unroll
    for (int kt = 0; kt < 2; ++kt)
      bf3[ntl][kt] = *(const bf8*)(w3f + ((size_t)(kt * 8 + (2 * w + ntl)) * 64 + l) * 8);
#pragma unroll
  for (int mt = 0; mt < 4; ++mt)
#pragma unroll
    for (int kt = 0; kt < 2; ++kt) {
      bf8 afrag = *(const bf8*)(x2b + (mt * 16 + lc) * 72 + kt * 32 + g * 8);
#pragma unroll
      for (int ntl = 0; ntl < 2; ++ntl)
        c3[mt][ntl] = __builtin_amdgcn_mfma_f32_16x16x32_bf16(afrag, bf3[ntl][kt], c3[mt][ntl], 0, 0, 0);
    }

#pragma unroll
  for (int ntl = 0; ntl < 2; ++ntl) {
    float s = 0.f, q = 0.f;
#pragma unroll
    for (int mt = 0; mt < 4; ++mt)
#pragma unroll
      for (int r = 0; r < 4; ++r) { float v = c3[mt][ntl][r]; s += v; q = fmaf(v, v, q); }
    s += __shfl_xor(s, 16, 64); s += __shfl_xor(s, 32, 64);
    q += __shfl_xor(q, 16, 64); q += __shfl_xor(q, 32, 64);
    const int ch = w * 32 + ntl * 16 + lc;
    float mu  = s * (1.f / NPT);
    float inv = rsqrtf(q * (1.f / NPT) - mu * mu + EPS);
    float a = inv * pg3[ch];
    float bb = fmaf(-mu, a, pbe3[ch]);
    float m = 0.f;
#pragma unroll
    for (int mt = 0; mt < 4; ++mt)
#pragma unroll
      for (int r = 0; r < 4; ++r) m += lrelu(fmaf(c3[mt][ntl][r], a, bb));
    m += __shfl_xor(m, 16, 64); m += __shfl_xor(m, 32, 64);
    if (g == 0) xbar[ch] = m * (1.f / NPT);
  }
  __syncthreads();

  {
    const int d = t & 127, h = t >> 7;
    float a = 0.f;
#pragma unroll 8
    for (int c = h * 64; c < h * 64 + 64; ++c) a = fmaf(xbar[c], pw4[c * 128 + d], a);
    ps[t] = a;
  }
  __syncthreads();
  if (t < 128) emb[(size_t)p * 128 + t] = f2bf(ps[t] + ps[t + 128] + pb4[t]);
}

// ==================== kernel 2: MFMA tail, G=8 b's per block ====================
// A layout in LDS: [b_loc][9][SP] bf16, row 8 = zeros (2-tap overflow).
// Wave w owns m-tile w = rows w*16..w*16+15 = b's {2w, 2w+1}.
template<int KT, int NT, int TS, int SPI, int SPO, bool ACT>
__device__ __forceinline__ void mfma_conv(const unsigned short* __restrict__ xin,
    unsigned short* __restrict__ xout, const unsigned short* __restrict__ wfr,
    const float* __restrict__ bias, int w, int l) {
  const int g = l >> 4, lc = l & 15;
  const int arow = w * 16 + lc, abl = arow >> 3, an = arow & 7;
  f4 acc[NT];
#pragma unroll
  for (int nt = 0; nt < NT; ++nt) acc[nt] = f4{0.f, 0.f, 0.f, 0.f};
#pragma unroll
  for (int kt = 0; kt < KT; ++kt) {
    const int k0 = kt * 32 + g * 8;
    const int tap = k0 / TS, c = k0 - tap * TS;
    bf8 a = *(const bf8*)(xin + (abl * 9 + an + tap) * SPI + c);
#pragma unroll
    for (int nt = 0; nt < NT; ++nt) {
      bf8 b = *(const bf8*)(wfr + ((size_t)(kt * NT + nt) * 64 + l) * 8);
      acc[nt] = __builtin_amdgcn_mfma_f32_16x16x32_bf16(a, b, acc[nt], 0, 0, 0);
    }
  }
  const int orow0 = w * 16 + g * 4;
#pragma unroll
  for (int nt = 0; nt < NT; ++nt) {
    const float bv = bias[nt * 16 + lc];
#pragma unroll
    for (int r = 0; r < 4; ++r) {
      const int rr = orow0 + r, obl = rr >> 3, on = rr & 7;
      float v = acc[nt][r] + bv;
      if (ACT) v = lrelu(v);
      xout[(obl * 9 + on) * SPO + nt * 16 + lc] = f2bf(v);
    }
  }
}

// dense 512->128 over [8 b][8 n][64 ch] (K-split over 4 waves, partials to LDS)
__device__ __forceinline__ void mfma_dense512(const unsigned short* __restrict__ xin,
    float* __restrict__ P, const unsigned short* __restrict__ wfr, int w, int l) {
  const int g = l >> 4, lc = l & 15;
  const int bl = lc & 7;                 // rows 8-15 duplicate rows 0-7
  f4 acc[8];
#pragma unroll
  for (int nt = 0; nt < 8; ++nt) acc[nt] = f4{0.f, 0.f, 0.f, 0.f};
#pragma unroll
  for (int kt2 = 0; kt2 < 4; ++kt2) {
    const int kt = w * 4 + kt2;
    const int k0 = kt * 32 + g * 8;
    const int n = k0 >> 6, c = k0 & 63;
    bf8 a = *(const bf8*)(xin + (bl * 9 + n) * 72 + c);
#pragma unroll
    for (int nt = 0; nt < 8; ++nt) {
      bf8 b = *(const bf8*)(wfr + ((size_t)(kt * 8 + nt) * 64 + l) * 8);
      acc[nt] = __builtin_amdgcn_mfma_f32_16x16x32_bf16(a, b, acc[nt], 0, 0, 0);
    }
  }
  if (g < 2) {
#pragma unroll
    for (int nt = 0; nt < 8; ++nt)
#pragma unroll
      for (int r = 0; r < 4; ++r) {
        const int rr = g * 4 + r;       // 0..7
        P[(w * 8 + rr) * 128 + nt * 16 + lc] = acc[nt][r];
      }
  }
}

__global__ __launch_bounds__(THREADS)
void tail_mfma_kernel(const unsigned short* __restrict__ emb, const float* __restrict__ state,
    const unsigned short* __restrict__ wf,
    const float* __restrict__ mb1, const float* __restrict__ mb2, const float* __restrict__ mb3,
    const float* __restrict__ mb4, const float* __restrict__ mdb,
    const float* __restrict__ sb1, const float* __restrict__ sb2, const float* __restrict__ sb3,
    const float* __restrict__ sb4, const float* __restrict__ sdb,
    float* __restrict__ femb, float* __restrict__ semb)
{
  const int t = threadIdx.x, l = t & 63, w = t >> 6;
  const bool merge = blockIdx.x < 128;
  const int bg = merge ? blockIdx.x : blockIdx.x - 128;

  __shared__ unsigned short lds[24768];           // 49.5 KB
  unsigned short* BufX = lds;                     // [8][9][136] xin / L3-out [8][9][72] / partials
  unsigned short* BufY = lds + 9792;              // L1-out [8][9][136] / L4-out [8][9][72]
  unsigned short* BufZ = lds + 19584;             // L2-out [8][9][72]

  // zero: BufX fully; BufY row-8 (stride 136); BufZ row-8 (stride 72)
  { unsigned* z = (unsigned*)BufX; for (int i = t; i < 4896; i += THREADS) z[i] = 0; }
  for (int i = t; i < 8 * 136; i += THREADS) BufY[((i / 136) * 9 + 8) * 136 + (i % 136)] = 0;
  for (int i = t; i < 8 * 72;  i += THREADS) BufZ[((i / 72)  * 9 + 8) * 72  + (i % 72)]  = 0;

  if (merge) {
    for (int i = t; i < 1024; i += THREADS) {     // 8b x 8n x 16 chunks of 8 bf16
      int bl = i >> 7, rem = i & 127, n = rem >> 4, sl = rem & 15;
      bf8 v = *(const bf8*)(emb + (size_t)((bg * 8 + bl) * 8 + n) * 128 + sl * 8);
      *(bf8*)(BufX + (bl * 9 + n) * 136 + sl * 8) = v;
    }
  } else {
    for (int i = t; i < 2304; i += THREADS) {     // 8b x 8n x 36
      int bl = i / 288, rem = i % 288, n = rem / 36, c = rem % 36;
      BufX[(bl * 9 + n) * 48 + c] = f2bf(state[((size_t)(bg * 8 + bl) * 8 + n) * 36 + c]);
    }
  }
  __syncthreads();

  if (merge) mfma_conv<8, 8, 128, 136, 136, true>(BufX, BufY, wf + WOFF_MW1, mb1, w, l);
  else       mfma_conv<3, 8,  48,  48, 136, true>(BufX, BufY, wf + WOFF_SW1, sb1, w, l);
  __syncthreads();
  if (merge) mfma_conv<8, 4, 128, 136, 72, true>(BufY, BufZ, wf + WOFF_MW2, mb2, w, l);
  else       mfma_conv<8, 4, 128, 136, 72, true>(BufY, BufZ, wf + WOFF_SW2, sb2, w, l);
  // BufX is dead (conv1 reads done 1 barrier ago); set up L3's zero row-8 (stride 72)
  __syncthreads();
  for (int i = t; i < 8 * 72; i += THREADS) BufX[((i / 72) * 9 + 8) * 72 + (i % 72)] = 0;
  __syncthreads();
  if (merge) mfma_conv<4, 4, 64, 72, 72, true>(BufZ, BufX, wf + WOFF_MW3, mb3, w, l);
  else       mfma_conv<4, 4, 64, 72, 72, true>(BufZ, BufX, wf + WOFF_SW3, sb3, w, l);
  __syncthreads();
  if (merge) mfma_conv<4, 4, 64, 72, 72, true >(BufX, BufY, wf + WOFF_MW4, mb4, w, l);
  else       mfma_conv<4, 4, 64, 72, 72, false>(BufX, BufY, wf + WOFF_SW4, sb4, w, l);
  __syncthreads();

  float* P = (float*)lds;                         // 16 KB partials (BufX region, dead)
  mfma_dense512(BufY, P, wf + (merge ? WOFF_MDW : WOFF_SDW), w, l);
  __syncthreads();

  const float* bias = merge ? mdb : sdb;
  float* outg = (merge ? femb : semb) + (size_t)bg * 1024;
  for (int i = t; i < 1024; i += THREADS) {
    int ch = i & 127, b = i >> 7;
    outg[i] = bias[ch] + P[(0 * 8 + b) * 128 + ch] + P[(1 * 8 + b) * 128 + ch]
                       + P[(2 * 8 + b) * 128 + ch] + P[(3 * 8 + b) * 128 + ch];
  }
}

// ==================== kernel 3: control head, one wave per b ====================
template<int CIN, int COUT, bool ACT>
__device__ __forceinline__ void wave_dense(const float* __restrict__ in, float* __restrict__ out,
                                           const float* __restrict__ W, const float* __restrict__ bias, int l) {
  if constexpr (COUT >= 64) {
    constexpr int NC = COUT / 64;
    const int d0 = l * NC;
    float acc[NC];
#pragma unroll
    for (int k = 0; k < NC; ++k) acc[k] = bias[d0 + k];
#pragma unroll 4
    for (int c4 = 0; c4 < CIN / 4; ++c4) {
      v4f x4 = *(const v4f*)(in + 4 * c4);
#pragma unroll
      for (int j = 0; j < 4; ++j) {
        const float* wr = W + (4 * c4 + j) * COUT + d0;
#pragma unroll
        for (int k = 0; k < NC; ++k) acc[k] = fmaf(x4[j], wr[k], acc[k]);
      }
    }
#pragma unroll
    for (int k = 0; k < NC; ++k) out[d0 + k] = ACT ? lrelu(acc[k]) : acc[k];
  } else {
    if (l < COUT) {
      float acc = bias[l];
#pragma unroll 4
      for (int c4 = 0; c4 < CIN / 4; ++c4) {
        v4f x4 = *(const v4f*)(in + 4 * c4);
#pragma unroll
        for (int j = 0; j < 4; ++j) acc = fmaf(x4[j], W[(4 * c4 + j) * COUT + l], acc);
      }
      out[l] = ACT ? lrelu(acc) : acc;
    }
  }
}

__global__ __launch_bounds__(THREADS)
void head_kernel(const float* __restrict__ femb, const float* __restrict__ semb,
    const float* __restrict__ cw1, const float* __restrict__ cb1,
    const float* __restrict__ cw2, const float* __restrict__ cb2,
    const float* __restrict__ cw3, const float* __restrict__ cb3,
    const float* __restrict__ cw4, const float* __restrict__ cb4,
    float* __restrict__ out)
{
  const int t = threadIdx.x, l = t & 63, w = t >> 6;
  const int b = blockIdx.x * 4 + w;
  __shared__ float cat[4][256];
  __shared__ float hb[4][232];    // h1 128 | h2 64 | h3 32 (+pad)

  cat[w][l]       = femb[(size_t)b * 128 + l];
  cat[w][64 + l]  = femb[(size_t)b * 128 + 64 + l];
  cat[w][128 + l] = semb[(size_t)b * 128 + l];
  cat[w][192 + l] = semb[(size_t)b * 128 + 64 + l];
  __syncthreads();
  wave_dense<256, 128, true>(cat[w], hb[w], cw1, cb1, l);
  __syncthreads();
  wave_dense<128, 64, true>(hb[w], hb[w] + 128, cw2, cb2, l);
  __syncthreads();
  wave_dense<64, 32, true>(hb[w] + 128, hb[w] + 192, cw3, cb3, l);
  __syncthreads();
  if (l < 4) {
    float acc = cb4[l];
#pragma unroll
    for (int c = 0; c < 32; ++c) acc = fmaf(hb[w][192 + c], cw4[c * 4 + l], acc);
    out[(size_t)b * 4 + l] = (l == 0) ? 21.f / (1.f + expf(-acc)) : 6.f * tanhf(acc);
  }
}

extern "C" void kernel_launch(void* const* d_in, const int* in_sizes, int n_in,
                              void* d_out, int out_size, void* d_ws, size_t ws_size,
                              hipStream_t stream) {
  const float* p[44];
  for (int i = 0; i < 44; ++i) p[i] = (const float*)d_in[i];

  unsigned short* emb_bf = (unsigned short*)d_ws;                      // 2 MB
  float* femb = (float*)((char*)d_ws + 2097152);                       // 512 KB
  float* semb = (float*)((char*)d_ws + 2621440);                       // 512 KB
  unsigned short* wf = (unsigned short*)((char*)d_ws + 3145728);       // 504 KB

  prep_weights<<<123, THREADS, 0, stream>>>(
      p[6], p[10],
      p[16], p[18], p[20], p[22], p[24],
      p[26], p[28], p[30], p[32], p[34],
      wf);

  pointnet_kernel<<<1024 * S, THREADS, 0, stream>>>(
      p[0],
      p[2], p[4], p[5],
      wf + WOFF_PNW2, p[8], p[9],
      wf + WOFF_PNW3, p[12], p[13],
      p[14], p[15],
      emb_bf);

  tail_mfma_kernel<<<256, THREADS, 0, stream>>>(
      emb_bf, p[1], wf,
      p[17], p[19], p[21], p[23], p[25],
      p[27], p[29], p[31], p[33], p[35],
      femb, semb);

  head_kernel<<<256, THREADS, 0, stream>>>(
      femb, semb,
      p[36], p[37], p[38], p[39], p[40], p[41], p[42], p[43],
      (float*)d_out);
}

// Round 7
// 95.915 us; speedup vs baseline: 5.1588x; 1.0002x over previous
//
#include <hip/hip_runtime.h>
#include <math.h>

#define THREADS 256

constexpr int S   = 8;
constexpr int NPT = 64;
constexpr int SD  = 36;
constexpr float EPS = 1e-5f;

typedef float v4f __attribute__((ext_vector_type(4)));
typedef __attribute__((ext_vector_type(8))) short bf8;   // 8 bf16 (4 VGPR)
typedef __attribute__((ext_vector_type(4))) float f4;    // MFMA accumulator

__device__ __forceinline__ float lrelu(float x) { return x > 0.f ? x : 0.01f * x; }

// float -> bf16 round-to-nearest-even
__device__ __forceinline__ unsigned short f2bf(float x) {
  union { float f; unsigned u; } v; v.f = x;
  unsigned r = v.u + 0x7FFFu + ((v.u >> 16) & 1u);
  return (unsigned short)(r >> 16);
}

// ==================== fragment packing (one-time prep) ====================
// B-fragment: frag f = kt*NT + nt; lane l holds n = nt*16 + (l&15),
// k = kt*32 + (l>>4)*8 + j, j=0..7. TS>0: 2-tap conv weight [2][CIN][N] with
// tap stride TS (zero-pad c >= CIN). TS==0: flat [K][N].
__device__ __forceinline__ void pack_frag(const float* __restrict__ src, unsigned short* __restrict__ dst,
                                          int slot, int NT, int TS, int CIN, int N) {
  const int f = slot >> 6, l = slot & 63;
  const int nt = f % NT, kt = f / NT;
  const int n = nt * 16 + (l & 15), g = (l >> 4);
  unsigned short* d = dst + (size_t)f * 512 + l * 8;
#pragma unroll
  for (int j = 0; j < 8; ++j) {
    int k = kt * 32 + g * 8 + j;
    float v;
    if (TS > 0) { int tap = k / TS, c = k - tap * TS; v = (c < CIN) ? src[(tap * CIN + c) * N + n] : 0.f; }
    else        v = src[k * N + n];
    d[j] = f2bf(v);
  }
}

// fragment-region offsets in u16 units (frag = 512 u16)
#define WOFF_PNW2 0
#define WOFF_PNW3 2048
#define WOFF_MW1  10240
#define WOFF_MW2  43008
#define WOFF_MW3  59392
#define WOFF_MW4  67584
#define WOFF_MDW  75776
#define WOFF_SW1  141312
#define WOFF_SW2  153600
#define WOFF_SW3  169984
#define WOFF_SW4  178176
#define WOFF_SDW  186368
// total 492 frags = 251904 u16 = 503808 B

__global__ void prep_weights(const float* __restrict__ pw2, const float* __restrict__ pw3,
    const float* __restrict__ mw1, const float* __restrict__ mw2, const float* __restrict__ mw3,
    const float* __restrict__ mw4, const float* __restrict__ mdw,
    const float* __restrict__ sw1, const float* __restrict__ sw2, const float* __restrict__ sw3,
    const float* __restrict__ sw4, const float* __restrict__ sdw,
    unsigned short* __restrict__ wf) {
  const int slot = blockIdx.x * 256 + threadIdx.x;
  if      (slot <   256) pack_frag(pw2, wf + WOFF_PNW2, slot,          4,   0,   0,  64);
  else if (slot <  1280) pack_frag(pw3, wf + WOFF_PNW3, slot - 256,    8,   0,   0, 128);
  else if (slot <  5376) pack_frag(mw1, wf + WOFF_MW1,  slot - 1280,   8, 128, 128, 128);
  else if (slot <  7424) pack_frag(mw2, wf + WOFF_MW2,  slot - 5376,   4, 128, 128,  64);
  else if (slot <  8448) pack_frag(mw3, wf + WOFF_MW3,  slot - 7424,   4,  64,  64,  64);
  else if (slot <  9472) pack_frag(mw4, wf + WOFF_MW4,  slot - 8448,   4,  64,  64,  64);
  else if (slot < 17664) pack_frag(mdw, wf + WOFF_MDW,  slot - 9472,   8,   0,   0, 128);
  else if (slot < 19200) pack_frag(sw1, wf + WOFF_SW1,  slot - 17664,  8,  48,  36, 128);
  else if (slot < 21248) pack_frag(sw2, wf + WOFF_SW2,  slot - 19200,  4, 128, 128,  64);
  else if (slot < 22272) pack_frag(sw3, wf + WOFF_SW3,  slot - 21248,  4,  64,  64,  64);
  else if (slot < 23296) pack_frag(sw4, wf + WOFF_SW4,  slot - 22272,  4,  64,  64,  64);
  else if (slot < 31488) pack_frag(sdw, wf + WOFF_SDW,  slot - 23296,  8,   0,   0, 128);
}

// ==================== kernel 1: pointnet (unchanged structure, bf16 emb out) ====================
template<int CIN, int COUT, int SPI, int SPO, int TN, int TD>
__device__ __forceinline__ void mm_sca(const float* __restrict__ in, float* __restrict__ out,
                                       const float* __restrict__ W, int t) {
  constexpr int ND = COUT / TD;
  static_assert((NPT / TN) * ND == THREADS, "tile");
  const int n0 = (t / ND) * TN, d0 = (t % ND) * TD;
  float acc[TN][TD]{};
#pragma unroll
  for (int c = 0; c < CIN; ++c) {
    float xv[TN], wv[TD];
#pragma unroll
    for (int i = 0; i < TN; ++i) xv[i] = in[(n0 + i) * SPI + c];
#pragma unroll
    for (int j = 0; j < TD; ++j) wv[j] = W[c * COUT + d0 + j];
#pragma unroll
    for (int i = 0; i < TN; ++i)
#pragma unroll
      for (int j = 0; j < TD; ++j) acc[i][j] = fmaf(xv[i], wv[j], acc[i][j]);
  }
#pragma unroll
  for (int i = 0; i < TN; ++i)
#pragma unroll
    for (int j = 0; j < TD; ++j) out[(n0 + i) * SPO + d0 + j] = acc[i][j];
}

__global__ __launch_bounds__(THREADS)
void pointnet_kernel(const float* __restrict__ fts,
    const float* __restrict__ pw1, const float* __restrict__ pg1, const float* __restrict__ pbe1,
    const unsigned short* __restrict__ w2f, const float* __restrict__ pg2, const float* __restrict__ pbe2,
    const unsigned short* __restrict__ w3f, const float* __restrict__ pg3, const float* __restrict__ pbe3,
    const float* __restrict__ pw4, const float* __restrict__ pb4,
    unsigned short* __restrict__ emb)
{
  const int p = blockIdx.x;            // b*S + s
  const int t = threadIdx.x;
  const int l = t & 63, w = t >> 6;
  const int g = l >> 4, lc = l & 15;

  __shared__ float xin[320];
  __shared__ float x1[64 * 36];
  __shared__ unsigned short x1b[64 * 40];
  __shared__ unsigned short x2b[64 * 72];
  __shared__ float ps[256], pss[256];
  __shared__ float aA[32], bA[32];
  __shared__ float xbar[128];

  { const float* src = fts + (size_t)p * 320;
    for (int i = t; i < 320; i += THREADS) xin[i] = src[i]; }
  __syncthreads();

  mm_sca<5, 32, 5, 36, 4, 2>(xin, x1, pw1, t);
  __syncthreads();

  {
    const int c = t & 31, gr = t >> 5;
    float s = 0.f, ss = 0.f;
#pragma unroll
    for (int k = 0; k < 8; ++k) { float v = x1[(gr + 8 * k) * 36 + c]; s += v; ss = fmaf(v, v, ss); }
    ps[t] = s; pss[t] = ss;
    __syncthreads();
    if (t < 32) {
      float S1 = 0.f, S2 = 0.f;
#pragma unroll
      for (int h = 0; h < 8; ++h) { S1 += ps[h * 32 + t]; S2 += pss[h * 32 + t]; }
      float mu  = S1 * (1.f / NPT);
      float inv = rsqrtf(S2 * (1.f / NPT) - mu * mu + EPS);
      float a = inv * pg1[t];
      aA[t] = a; bA[t] = fmaf(-mu, a, pbe1[t]);
    }
    __syncthreads();
    const float a = aA[c], bb = bA[c];
#pragma unroll
    for (int k = 0; k < 8; ++k) {
      int r = gr + 8 * k;
      x1b[r * 40 + c] = f2bf(lrelu(fmaf(x1[r * 36 + c], a, bb)));
    }
  }
  __syncthreads();

  // L2 MFMA
  f4 c2[4];
#pragma unroll
  for (int mt = 0; mt < 4; ++mt) c2[mt] = f4{0.f, 0.f, 0.f, 0.f};
  {
    bf8 bfrag = *(const bf8*)(w2f + ((size_t)w * 64 + l) * 8);
#pragma unroll
    for (int mt = 0; mt < 4; ++mt) {
      bf8 afrag = *(const bf8*)(x1b + (mt * 16 + lc) * 40 + g * 8);
      c2[mt] = __builtin_amdgcn_mfma_f32_16x16x32_bf16(afrag, bfrag, c2[mt], 0, 0, 0);
    }
  }
  {
    float s = 0.f, q = 0.f;
#pragma unroll
    for (int mt = 0; mt < 4; ++mt)
#pragma unroll
      for (int r = 0; r < 4; ++r) { float v = c2[mt][r]; s += v; q = fmaf(v, v, q); }
    s += __shfl_xor(s, 16, 64); s += __shfl_xor(s, 32, 64);
    q += __shfl_xor(q, 16, 64); q += __shfl_xor(q, 32, 64);
    const int ch = w * 16 + lc;
    float mu  = s * (1.f / NPT);
    float inv = rsqrtf(q * (1.f / NPT) - mu * mu + EPS);
    float a = inv * pg2[ch];
    float bb = fmaf(-mu, a, pbe2[ch]);
#pragma unroll
    for (int mt = 0; mt < 4; ++mt)
#pragma unroll
      for (int r = 0; r < 4; ++r) {
        int row = mt * 16 + g * 4 + r;
        x2b[row * 72 + ch] = f2bf(lrelu(fmaf(c2[mt][r], a, bb)));
      }
  }
  __syncthreads();

  // L3 MFMA
  f4 c3[4][2];
#pragma unroll
  for (int mt = 0; mt < 4; ++mt)
#pragma unroll
    for (int n = 0; n < 2; ++n) c3[mt][n] = f4{0.f, 0.f, 0.f, 0.f};
  bf8 bf3[2][2];
#pragma unroll
  for (int ntl = 0; ntl < 2; ++ntl)
#pragma unroll
    for (int kt = 0; kt < 2; ++kt)
      bf3[ntl][kt] = *(const bf8*)(w3f + ((size_t)(kt * 8 + (2 * w + ntl)) * 64 + l) * 8);
#pragma unroll
  for (int mt = 0; mt < 4; ++mt)
#pragma unroll
    for (int kt = 0; kt < 2; ++kt) {
      bf8 afrag = *(const bf8*)(x2b + (mt * 16 + lc) * 72 + kt * 32 + g * 8);
#pragma unroll
      for (int ntl = 0; ntl < 2; ++ntl)
        c3[mt][ntl] = __builtin_amdgcn_mfma_f32_16x16x32_bf16(afrag, bf3[ntl][kt], c3[mt][ntl], 0, 0, 0);
    }

#pragma unroll
  for (int ntl = 0; ntl < 2; ++ntl) {
    float s = 0.f, q = 0.f;
#pragma unroll
    for (int mt = 0; mt < 4; ++mt)
#pragma unroll
      for (int r = 0; r < 4; ++r) { float v = c3[mt][ntl][r]; s += v; q = fmaf(v, v, q); }
    s += __shfl_xor(s, 16, 64); s += __shfl_xor(s, 32, 64);
    q += __shfl_xor(q, 16, 64); q += __shfl_xor(q, 32, 64);
    const int ch = w * 32 + ntl * 16 + lc;
    float mu  = s * (1.f / NPT);
    float inv = rsqrtf(q * (1.f / NPT) - mu * mu + EPS);
    float a = inv * pg3[ch];
    float bb = fmaf(-mu, a, pbe3[ch]);
    float m = 0.f;
#pragma unroll
    for (int mt = 0; mt < 4; ++mt)
#pragma unroll
      for (int r = 0; r < 4; ++r) m += lrelu(fmaf(c3[mt][ntl][r], a, bb));
    m += __shfl_xor(m, 16, 64); m += __shfl_xor(m, 32, 64);
    if (g == 0) xbar[ch] = m * (1.f / NPT);
  }
  __syncthreads();

  {
    const int d = t & 127, h = t >> 7;
    float a = 0.f;
#pragma unroll 8
    for (int c = h * 64; c < h * 64 + 64; ++c) a = fmaf(xbar[c], pw4[c * 128 + d], a);
    ps[t] = a;
  }
  __syncthreads();
  if (t < 128) emb[(size_t)p * 128 + t] = f2bf(ps[t] + ps[t + 128] + pb4[t]);
}

// ==================== kernel 2: MFMA tail, G=8 b's per block ====================
// A layout in LDS: [b_loc][9][SP] bf16, row 8 = zeros (2-tap overflow).
// Wave w owns m-tile w = rows w*16..w*16+15 = b's {2w, 2w+1}.
template<int KT, int NT, int TS, int SPI, int SPO, bool ACT>
__device__ __forceinline__ void mfma_conv(const unsigned short* __restrict__ xin,
    unsigned short* __restrict__ xout, const unsigned short* __restrict__ wfr,
    const float* __restrict__ bias, int w, int l) {
  const int g = l >> 4, lc = l & 15;
  const int arow = w * 16 + lc, abl = arow >> 3, an = arow & 7;
  f4 acc[NT];
#pragma unroll
  for (int nt = 0; nt < NT; ++nt) acc[nt] = f4{0.f, 0.f, 0.f, 0.f};
#pragma unroll
  for (int kt = 0; kt < KT; ++kt) {
    const int k0 = kt * 32 + g * 8;
    const int tap = k0 / TS, c = k0 - tap * TS;
    bf8 a = *(const bf8*)(xin + (abl * 9 + an + tap) * SPI + c);
#pragma unroll
    for (int nt = 0; nt < NT; ++nt) {
      bf8 b = *(const bf8*)(wfr + ((size_t)(kt * NT + nt) * 64 + l) * 8);
      acc[nt] = __builtin_amdgcn_mfma_f32_16x16x32_bf16(a, b, acc[nt], 0, 0, 0);
    }
  }
  const int orow0 = w * 16 + g * 4;
#pragma unroll
  for (int nt = 0; nt < NT; ++nt) {
    const float bv = bias[nt * 16 + lc];
#pragma unroll
    for (int r = 0; r < 4; ++r) {
      const int rr = orow0 + r, obl = rr >> 3, on = rr & 7;
      float v = acc[nt][r] + bv;
      if (ACT) v = lrelu(v);
      xout[(obl * 9 + on) * SPO + nt * 16 + lc] = f2bf(v);
    }
  }
}

// dense 512->128 over [8 b][8 n][64 ch] (K-split over 4 waves, partials to LDS)
__device__ __forceinline__ void mfma_dense512(const unsigned short* __restrict__ xin,
    float* __restrict__ P, const unsigned short* __restrict__ wfr, int w, int l) {
  const int g = l >> 4, lc = l & 15;
  const int bl = lc & 7;                 // rows 8-15 duplicate rows 0-7
  f4 acc[8];
#pragma unroll
  for (int nt = 0; nt < 8; ++nt) acc[nt] = f4{0.f, 0.f, 0.f, 0.f};
#pragma unroll
  for (int kt2 = 0; kt2 < 4; ++kt2) {
    const int kt = w * 4 + kt2;
    const int k0 = kt * 32 + g * 8;
    const int n = k0 >> 6, c = k0 & 63;
    bf8 a = *(const bf8*)(xin + (bl * 9 + n) * 72 + c);
#pragma unroll
    for (int nt = 0; nt < 8; ++nt) {
      bf8 b = *(const bf8*)(wfr + ((size_t)(kt * 8 + nt) * 64 + l) * 8);
      acc[nt] = __builtin_amdgcn_mfma_f32_16x16x32_bf16(a, b, acc[nt], 0, 0, 0);
    }
  }
  if (g < 2) {
#pragma unroll
    for (int nt = 0; nt < 8; ++nt)
#pragma unroll
      for (int r = 0; r < 4; ++r) {
        const int rr = g * 4 + r;       // 0..7
        P[(w * 8 + rr) * 128 + nt * 16 + lc] = acc[nt][r];
      }
  }
}

__global__ __launch_bounds__(THREADS)
void tail_mfma_kernel(const unsigned short* __restrict__ emb, const float* __restrict__ state,
    const unsigned short* __restrict__ wf,
    const float* __restrict__ mb1, const float* __restrict__ mb2, const float* __restrict__ mb3,
    const float* __restrict__ mb4, const float* __restrict__ mdb,
    const float* __restrict__ sb1, const float* __restrict__ sb2, const float* __restrict__ sb3,
    const float* __restrict__ sb4, const float* __restrict__ sdb,
    float* __restrict__ femb, float* __restrict__ semb)
{
  const int t = threadIdx.x, l = t & 63, w = t >> 6;
  const bool merge = blockIdx.x < 128;
  const int bg = merge ? blockIdx.x : blockIdx.x - 128;

  __shared__ unsigned short lds[24768];           // 49.5 KB
  unsigned short* BufX = lds;                     // [8][9][136] xin / L3-out [8][9][72] / partials
  unsigned short* BufY = lds + 9792;              // L1-out [8][9][136] / L4-out [8][9][72]
  unsigned short* BufZ = lds + 19584;             // L2-out [8][9][72]

  // zero: BufX fully; BufY row-8 (stride 136); BufZ row-8 (stride 72)
  { unsigned* z = (unsigned*)BufX; for (int i = t; i < 4896; i += THREADS) z[i] = 0; }
  for (int i = t; i < 8 * 136; i += THREADS) BufY[((i / 136) * 9 + 8) * 136 + (i % 136)] = 0;
  for (int i = t; i < 8 * 72;  i += THREADS) BufZ[((i / 72)  * 9 + 8) * 72  + (i % 72)]  = 0;

  if (merge) {
    for (int i = t; i < 1024; i += THREADS) {     // 8b x 8n x 16 chunks of 8 bf16
      int bl = i >> 7, rem = i & 127, n = rem >> 4, sl = rem & 15;
      bf8 v = *(const bf8*)(emb + (size_t)((bg * 8 + bl) * 8 + n) * 128 + sl * 8);
      *(bf8*)(BufX + (bl * 9 + n) * 136 + sl * 8) = v;
    }
  } else {
    for (int i = t; i < 2304; i += THREADS) {     // 8b x 8n x 36
      int bl = i / 288, rem = i % 288, n = rem / 36, c = rem % 36;
      BufX[(bl * 9 + n) * 48 + c] = f2bf(state[((size_t)(bg * 8 + bl) * 8 + n) * 36 + c]);
    }
  }
  __syncthreads();

  if (merge) mfma_conv<8, 8, 128, 136, 136, true>(BufX, BufY, wf + WOFF_MW1, mb1, w, l);
  else       mfma_conv<3, 8,  48,  48, 136, true>(BufX, BufY, wf + WOFF_SW1, sb1, w, l);
  __syncthreads();
  if (merge) mfma_conv<8, 4, 128, 136, 72, true>(BufY, BufZ, wf + WOFF_MW2, mb2, w, l);
  else       mfma_conv<8, 4, 128, 136, 72, true>(BufY, BufZ, wf + WOFF_SW2, sb2, w, l);
  // BufX is dead (conv1 reads done 1 barrier ago); set up L3's zero row-8 (stride 72)
  __syncthreads();
  for (int i = t; i < 8 * 72; i += THREADS) BufX[((i / 72) * 9 + 8) * 72 + (i % 72)] = 0;
  __syncthreads();
  if (merge) mfma_conv<4, 4, 64, 72, 72, true>(BufZ, BufX, wf + WOFF_MW3, mb3, w, l);
  else       mfma_conv<4, 4, 64, 72, 72, true>(BufZ, BufX, wf + WOFF_SW3, sb3, w, l);
  __syncthreads();
  if (merge) mfma_conv<4, 4, 64, 72, 72, true >(BufX, BufY, wf + WOFF_MW4, mb4, w, l);
  else       mfma_conv<4, 4, 64, 72, 72, false>(BufX, BufY, wf + WOFF_SW4, sb4, w, l);
  __syncthreads();

  float* P = (float*)lds;                         // 16 KB partials (BufX region, dead)
  mfma_dense512(BufY, P, wf + (merge ? WOFF_MDW : WOFF_SDW), w, l);
  __syncthreads();

  const float* bias = merge ? mdb : sdb;
  float* outg = (merge ? femb : semb) + (size_t)bg * 1024;
  for (int i = t; i < 1024; i += THREADS) {
    int ch = i & 127, b = i >> 7;
    outg[i] = bias[ch] + P[(0 * 8 + b) * 128 + ch] + P[(1 * 8 + b) * 128 + ch]
                       + P[(2 * 8 + b) * 128 + ch] + P[(3 * 8 + b) * 128 + ch];
  }
}

// ==================== kernel 3: control head, one wave per b ====================
template<int CIN, int COUT, bool ACT>
__device__ __forceinline__ void wave_dense(const float* __restrict__ in, float* __restrict__ out,
                                           const float* __restrict__ W, const float* __restrict__ bias, int l) {
  if constexpr (COUT >= 64) {
    constexpr int NC = COUT / 64;
    const int d0 = l * NC;
    float acc[NC];
#pragma unroll
    for (int k = 0; k < NC; ++k) acc[k] = bias[d0 + k];
#pragma unroll 4
    for (int c4 = 0; c4 < CIN / 4; ++c4) {
      v4f x4 = *(const v4f*)(in + 4 * c4);
#pragma unroll
      for (int j = 0; j < 4; ++j) {
        const float* wr = W + (4 * c4 + j) * COUT + d0;
#pragma unroll
        for (int k = 0; k < NC; ++k) acc[k] = fmaf(x4[j], wr[k], acc[k]);
      }
    }
#pragma unroll
    for (int k = 0; k < NC; ++k) out[d0 + k] = ACT ? lrelu(acc[k]) : acc[k];
  } else {
    if (l < COUT) {
      float acc = bias[l];
#pragma unroll 4
      for (int c4 = 0; c4 < CIN / 4; ++c4) {
        v4f x4 = *(const v4f*)(in + 4 * c4);
#pragma unroll
        for (int j = 0; j < 4; ++j) acc = fmaf(x4[j], W[(4 * c4 + j) * COUT + l], acc);
      }
      out[l] = ACT ? lrelu(acc) : acc;
    }
  }
}

__global__ __launch_bounds__(THREADS)
void head_kernel(const float* __restrict__ femb, const float* __restrict__ semb,
    const float* __restrict__ cw1, const float* __restrict__ cb1,
    const float* __restrict__ cw2, const float* __restrict__ cb2,
    const float* __restrict__ cw3, const float* __restrict__ cb3,
    const float* __restrict__ cw4, const float* __restrict__ cb4,
    float* __restrict__ out)
{
  const int t = threadIdx.x, l = t & 63, w = t >> 6;
  const int b = blockIdx.x * 4 + w;
  __shared__ float cat[4][256];
  __shared__ float hb[4][232];    // h1 128 | h2 64 | h3 32 (+pad)

  cat[w][l]       = femb[(size_t)b * 128 + l];
  cat[w][64 + l]  = femb[(size_t)b * 128 + 64 + l];
  cat[w][128 + l] = semb[(size_t)b * 128 + l];
  cat[w][192 + l] = semb[(size_t)b * 128 + 64 + l];
  __syncthreads();
  wave_dense<256, 128, true>(cat[w], hb[w], cw1, cb1, l);
  __syncthreads();
  wave_dense<128, 64, true>(hb[w], hb[w] + 128, cw2, cb2, l);
  __syncthreads();
  wave_dense<64, 32, true>(hb[w] + 128, hb[w] + 192, cw3, cb3, l);
  __syncthreads();
  if (l < 4) {
    float acc = cb4[l];
#pragma unroll
    for (int c = 0; c < 32; ++c) acc = fmaf(hb[w][192 + c], cw4[c * 4 + l], acc);
    out[(size_t)b * 4 + l] = (l == 0) ? 21.f / (1.f + expf(-acc)) : 6.f * tanhf(acc);
  }
}

extern "C" void kernel_launch(void* const* d_in, const int* in_sizes, int n_in,
                              void* d_out, int out_size, void* d_ws, size_t ws_size,
                              hipStream_t stream) {
  const float* p[44];
  for (int i = 0; i < 44; ++i) p[i] = (const float*)d_in[i];

  unsigned short* emb_bf = (unsigned short*)d_ws;                      // 2 MB
  float* femb = (float*)((char*)d_ws + 2097152);                       // 512 KB
  float* semb = (float*)((char*)d_ws + 2621440);                       // 512 KB
  unsigned short* wf = (unsigned short*)((char*)d_ws + 3145728);       // 504 KB

  prep_weights<<<123, THREADS, 0, stream>>>(
      p[6], p[10],
      p[16], p[18], p[20], p[22], p[24],
      p[26], p[28], p[30], p[32], p[34],
      wf);

  pointnet_kernel<<<1024 * S, THREADS, 0, stream>>>(
      p[0],
      p[2], p[4], p[5],
      wf + WOFF_PNW2, p[8], p[9],
      wf + WOFF_PNW3, p[12], p[13],
      p[14], p[15],
      emb_bf);

  tail_mfma_kernel<<<256, THREADS, 0, stream>>>(
      emb_bf, p[1], wf,
      p[17], p[19], p[21], p[23], p[25],
      p[27], p[29], p[31], p[33], p[35],
      femb, semb);

  head_kernel<<<256, THREADS, 0, stream>>>(
      femb, semb,
      p[36], p[37], p[38], p[39], p[40], p[41], p[42], p[43],
      (float*)d_out);
}